// Round 1
// baseline (24861.359 us; speedup 1.0000x reference)
//
#include <hip/hip_runtime.h>
#include <cstdint>
#include <cstddef>

#define DEV_INLINE __device__ __forceinline__

// ---------------------------------------------------------------------------
// Generic GEMM: C[N,O] = X[N,128] @ W[O,128]^T + bias[O]
// 128x128 tile, K staged in 2 chunks of 64, 64KB LDS, 8x8 micro-tile,
// XOR-swizzled float2 LDS layout (swz = row>>3) -> conflict-free ds_read_b64.
// ---------------------------------------------------------------------------
__global__ __launch_bounds__(256) void gemm_xwt(
    const float* __restrict__ X, const float* __restrict__ W,
    const float* __restrict__ bias, float* __restrict__ C,
    int N, int O)
{
  __shared__ float2 Xs[128 * 32];
  __shared__ float2 Ws[128 * 32];
  const int tid = threadIdx.x;
  const int tm = tid >> 4;   // 0..15
  const int tn = tid & 15;   // 0..15
  const int bm = blockIdx.x * 128;
  const int bn = blockIdx.y * 128;

  float acc[8][8];
#pragma unroll
  for (int i = 0; i < 8; ++i)
#pragma unroll
    for (int j = 0; j < 8; ++j) acc[i][j] = 0.f;

#pragma unroll
  for (int kc = 0; kc < 2; ++kc) {
    __syncthreads();
#pragma unroll
    for (int w = 0; w < 8; ++w) {
      int f = tid + 256 * w;   // float4 slot 0..2047
      int row = f >> 4;        // 0..127
      int s4 = f & 15;         // 0..15
      int swz = row >> 3;      // 0..15
      int s2 = s4 * 2;
      float4 xv = make_float4(0.f, 0.f, 0.f, 0.f);
      int gr = bm + row;
      if (gr < N) xv = *reinterpret_cast<const float4*>(X + (size_t)gr * 128 + kc * 64 + s4 * 4);
      Xs[row * 32 + ((s2    ) ^ swz)] = make_float2(xv.x, xv.y);
      Xs[row * 32 + ((s2 + 1) ^ swz)] = make_float2(xv.z, xv.w);
      float4 wv = make_float4(0.f, 0.f, 0.f, 0.f);
      int gw = bn + row;
      if (gw < O) wv = *reinterpret_cast<const float4*>(W + (size_t)gw * 128 + kc * 64 + s4 * 4);
      Ws[row * 32 + ((s2    ) ^ swz)] = make_float2(wv.x, wv.y);
      Ws[row * 32 + ((s2 + 1) ^ swz)] = make_float2(wv.z, wv.w);
    }
    __syncthreads();
#pragma unroll
    for (int k2 = 0; k2 < 32; ++k2) {
      float2 xr[8], wr[8];
#pragma unroll
      for (int i = 0; i < 8; ++i) xr[i] = Xs[(tm * 8 + i) * 32 + (k2 ^ tm)];
#pragma unroll
      for (int j = 0; j < 8; ++j) wr[j] = Ws[(tn * 8 + j) * 32 + (k2 ^ tn)];
#pragma unroll
      for (int i = 0; i < 8; ++i)
#pragma unroll
        for (int j = 0; j < 8; ++j)
          acc[i][j] += xr[i].x * wr[j].x + xr[i].y * wr[j].y;
    }
  }

#pragma unroll
  for (int i = 0; i < 8; ++i) {
    int r = bm + tm * 8 + i;
    if (r < N) {
#pragma unroll
      for (int j = 0; j < 8; ++j) {
        int c = bn + tn * 8 + j;
        if (c < O) C[(size_t)r * O + c] = acc[i][j] + bias[c];
      }
    }
  }
}

// ---------------------------------------------------------------------------
// Sparse row scan: H[M,128] = A[M,K] @ Xs[K,128], A is ~0.3% dense.
// One block (4 waves) per row; ballot over nonzeros; broadcast & accumulate.
// ---------------------------------------------------------------------------
__global__ __launch_bounds__(256) void spmv_scan(
    const float* __restrict__ A, const float* __restrict__ Xs,
    float* __restrict__ H, int M, int K)
{
  int row = blockIdx.x;
  int tid = threadIdx.x, wave = tid >> 6, lane = tid & 63;
  const float4* Arow = reinterpret_cast<const float4*>(A + (size_t)row * K);
  int K4 = K >> 2;  // K is always a multiple of 4 here
  float acc0 = 0.f, acc1 = 0.f;
  for (int base = wave * 64; base < K4; base += 256) {
    int q = base + lane;
    float4 a = (q < K4) ? Arow[q] : make_float4(0.f, 0.f, 0.f, 0.f);
#pragma unroll
    for (int c = 0; c < 4; ++c) {
      float av = (c == 0) ? a.x : (c == 1) ? a.y : (c == 2) ? a.z : a.w;
      unsigned long long mm = __ballot(av != 0.f);
      while (mm) {
        int b = __builtin_ctzll(mm);
        mm &= mm - 1;
        float v = __shfl(av, b);
        int jj = (base + b) * 4 + c;
        const float* xr = Xs + (size_t)jj * 128;
        acc0 += v * xr[lane];
        acc1 += v * xr[lane + 64];
      }
    }
  }
  __shared__ float red[4][128];
  red[wave][lane] = acc0;
  red[wave][lane + 64] = acc1;
  __syncthreads();
  if (wave == 0) {
    float r0 = red[0][lane] + red[1][lane] + red[2][lane] + red[3][lane];
    float r1 = red[0][lane + 64] + red[1][lane + 64] + red[2][lane + 64] + red[3][lane + 64];
    H[(size_t)row * 128 + lane] = r0;
    H[(size_t)row * 128 + 64 + lane] = r1;
  }
}

// ---------------------------------------------------------------------------
// Block reductions (blockDim.x == 256)
// ---------------------------------------------------------------------------
DEV_INLINE float br_max(float v, float* red) {
  int tid = threadIdx.x;
  red[tid] = v; __syncthreads();
#pragma unroll
  for (int s = 128; s > 0; s >>= 1) { if (tid < s) red[tid] = fmaxf(red[tid], red[tid + s]); __syncthreads(); }
  float r = red[0]; __syncthreads();
  return r;
}
DEV_INLINE float br_sum(float v, float* red) {
  int tid = threadIdx.x;
  red[tid] = v; __syncthreads();
#pragma unroll
  for (int s = 128; s > 0; s >>= 1) { if (tid < s) red[tid] += red[tid + s]; __syncthreads(); }
  float r = red[0]; __syncthreads();
  return r;
}

// ---------------------------------------------------------------------------
// Per-row: softmax(logits) -> p; tcp = <p, cls>; lsum = sum(cls);
// lse2 = log_softmax of p (softmax-of-softmax in the reference): max(p) = 1/Z1.
// ce[row] = tcp - lsum*(m2 + log Z2);   scaled[row,:] = tcp * src[row,:]
// ---------------------------------------------------------------------------
__global__ __launch_bounds__(256) void rowops_kernel(
    const float* __restrict__ logits, const float* __restrict__ cls,
    const float* __restrict__ src, float* __restrict__ scaled,
    float* __restrict__ ce, int N)
{
  __shared__ float ls[1500];
  __shared__ float red[256];
  __shared__ float tbc;
  int row = blockIdx.x;
  int tid = threadIdx.x;
  const float* lr = logits + (size_t)row * 1500;
  float m = -3.4e38f;
  for (int j = tid; j < 1500; j += 256) { float v = lr[j]; ls[j] = v; m = fmaxf(m, v); }
  float m1 = br_max(m, red);
  float z = 0.f;
  for (int j = tid; j < 1500; j += 256) { float e = expf(ls[j] - m1); ls[j] = e; z += e; }
  float Z1 = br_sum(z, red);
  float invZ1 = 1.0f / Z1;
  float m2 = invZ1;   // max(p) == exp(0)/Z1 exactly
  const float* cr = cls + (size_t)row * 1500;
  float t = 0.f, lsum = 0.f, z2 = 0.f;
  for (int j = tid; j < 1500; j += 256) {
    float p = ls[j] * invZ1;
    float c = cr[j];
    t += c * p; lsum += c; z2 += expf(p - m2);
  }
  t = br_sum(t, red);
  lsum = br_sum(lsum, red);
  z2 = br_sum(z2, red);
  if (tid == 0) { ce[row] = t - lsum * (m2 + logf(z2)); tbc = t; }
  __syncthreads();
  if (tid < 128) scaled[(size_t)row * 128 + tid] = tbc * src[(size_t)row * 128 + tid];
}

// ---------------------------------------------------------------------------
// GRU elementwise: gi/gh are [N,384] (ir|iz|in, hr|hz|hn), h is [N,128]
// ---------------------------------------------------------------------------
__global__ __launch_bounds__(256) void gru_elem(
    const float* __restrict__ gi, const float* __restrict__ gh,
    const float* __restrict__ h, float* __restrict__ out, int N)
{
  int idx = blockIdx.x * 256 + threadIdx.x;
  if (idx >= N * 128) return;
  int i = idx >> 7, d = idx & 127;
  const float* gir = gi + (size_t)i * 384;
  const float* ghr = gh + (size_t)i * 384;
  float ir = gir[d], iz = gir[128 + d], inn = gir[256 + d];
  float hr = ghr[d], hz = ghr[128 + d], hn = ghr[256 + d];
  float r = 1.f / (1.f + expf(-(ir + hr)));
  float zz = 1.f / (1.f + expf(-(iz + hz)));
  float n = tanhf(inn + r * hn);
  float hv = h[idx];
  out[idx] = (1.f - zz) * n + zz * hv;
}

// ---------------------------------------------------------------------------
// Fuse scores: s0[i] = relu(<e0[i],W2>+b2), s1[i] = relu(<e1[i],W3>+b3)
// one wave per row
// ---------------------------------------------------------------------------
__global__ __launch_bounds__(256) void fuse_scores(
    const float* __restrict__ e0, const float* __restrict__ e1,
    const float* __restrict__ W2, const float* __restrict__ b2,
    const float* __restrict__ W3, const float* __restrict__ b3,
    float* __restrict__ s0, float* __restrict__ s1, int N)
{
  int lane = threadIdx.x & 63;
  int wave = (blockIdx.x * 256 + threadIdx.x) >> 6;
  if (wave >= N) return;
  float a0 = e0[(size_t)wave * 128 + lane] * W2[lane] + e0[(size_t)wave * 128 + 64 + lane] * W2[64 + lane];
  float a1 = e1[(size_t)wave * 128 + lane] * W3[lane] + e1[(size_t)wave * 128 + 64 + lane] * W3[64 + lane];
#pragma unroll
  for (int o = 32; o > 0; o >>= 1) { a0 += __shfl_down(a0, o); a1 += __shfl_down(a1, o); }
  if (lane == 0) {
    s0[wave] = fmaxf(a0 + b2[0], 0.f);
    s1[wave] = fmaxf(a1 + b3[0], 0.f);
  }
}

// den[0..3] = {max(s0), sum exp(s0-max), max(s1), sum exp(s1-max)} -- softmax over NODE axis
__global__ __launch_bounds__(1024) void softmax_denom(
    const float* __restrict__ s0, const float* __restrict__ s1,
    float* __restrict__ den, int N)
{
  __shared__ float red[1024];
  int tid = threadIdx.x;
  float m = -3.4e38f;
  for (int i = tid; i < N; i += 1024) m = fmaxf(m, s0[i]);
  red[tid] = m; __syncthreads();
  for (int s = 512; s > 0; s >>= 1) { if (tid < s) red[tid] = fmaxf(red[tid], red[tid + s]); __syncthreads(); }
  float m0 = red[0]; __syncthreads();
  float z = 0.f;
  for (int i = tid; i < N; i += 1024) z += expf(s0[i] - m0);
  red[tid] = z; __syncthreads();
  for (int s = 512; s > 0; s >>= 1) { if (tid < s) red[tid] += red[tid + s]; __syncthreads(); }
  float Z0 = red[0]; __syncthreads();
  m = -3.4e38f;
  for (int i = tid; i < N; i += 1024) m = fmaxf(m, s1[i]);
  red[tid] = m; __syncthreads();
  for (int s = 512; s > 0; s >>= 1) { if (tid < s) red[tid] = fmaxf(red[tid], red[tid + s]); __syncthreads(); }
  float m1 = red[0]; __syncthreads();
  z = 0.f;
  for (int i = tid; i < N; i += 1024) z += expf(s1[i] - m1);
  red[tid] = z; __syncthreads();
  for (int s = 512; s > 0; s >>= 1) { if (tid < s) red[tid] += red[tid + s]; __syncthreads(); }
  if (tid == 0) { den[0] = m0; den[1] = red[0] ? 0 : 0; den[1] = Z0; den[2] = m1; den[3] = red[0]; }
}

__global__ __launch_bounds__(256) void fuse_emb(
    const float* __restrict__ e0, const float* __restrict__ e1,
    const float* __restrict__ s0, const float* __restrict__ s1,
    const float* __restrict__ den, float* __restrict__ out, int N)
{
  int idx = blockIdx.x * 256 + threadIdx.x;
  if (idx >= N * 128) return;
  int i = idx >> 7;
  float a0 = expf(s0[i] - den[0]) / den[1];
  float a1 = expf(s1[i] - den[2]) / den[3];
  out[idx] = fmaxf(a0 * e0[idx] + a1 * e1[idx], 0.f);
}

// ---------------------------------------------------------------------------
// Edge losses: accumulate -log_sigmoid terms into per-block partials (deterministic)
// ---------------------------------------------------------------------------
__global__ __launch_bounds__(256) void edge_d_kernel(
    const int* __restrict__ ud, const float* __restrict__ fe,
    const float* __restrict__ rel, float* __restrict__ partial, int En)
{
  int lane = threadIdx.x & 63;
  int wid = threadIdx.x >> 6;
  int gw = blockIdx.x * 4 + wid;
  int nw = gridDim.x * 4;
  float acc = 0.f;
  for (int e = gw; e < En; e += nw) {
    int4 ei = *reinterpret_cast<const int4*>(ud + (size_t)e * 4);
    const float* fi = fe + (size_t)ei.x * 128;
    const float* fj = fe + (size_t)ei.y * 128;
    const float* rr = rel + (size_t)ei.w * 128;
    float t0 = tanhf(fi[lane] + fj[lane]);
    float t1 = tanhf(fi[lane + 64] + fj[lane + 64]);
    float d = rr[lane] * t0 + rr[lane + 64] * t1;
#pragma unroll
    for (int o = 32; o > 0; o >>= 1) d += __shfl_down(d, o);
    if (lane == 0) {
      float x = (float)ei.z * d;
      acc += (x >= 0.f) ? log1pf(expf(-x)) : (-x + log1pf(expf(x)));
    }
  }
  __shared__ float red[4];
  if (lane == 0) red[wid] = acc;
  __syncthreads();
  if (threadIdx.x == 0) partial[blockIdx.x] = red[0] + red[1] + red[2] + red[3];
}

__global__ __launch_bounds__(256) void edge_s_kernel(
    const int* __restrict__ us, const float* __restrict__ fe,
    float* __restrict__ partial, int En)
{
  int lane = threadIdx.x & 63;
  int wid = threadIdx.x >> 6;
  int gw = blockIdx.x * 4 + wid;
  int nw = gridDim.x * 4;
  float acc = 0.f;
  for (int e = gw; e < En; e += nw) {
    int i = us[(size_t)e * 3], j = us[(size_t)e * 3 + 1], lab = us[(size_t)e * 3 + 2];
    const float* fi = fe + (size_t)i * 128;
    const float* fj = fe + (size_t)j * 128;
    float d = fi[lane] * fj[lane] + fi[lane + 64] * fj[lane + 64];
#pragma unroll
    for (int o = 32; o > 0; o >>= 1) d += __shfl_down(d, o);
    if (lane == 0) {
      float x = (float)lab * d;
      acc += (x >= 0.f) ? log1pf(expf(-x)) : (-x + log1pf(expf(x)));
    }
  }
  __shared__ float red[4];
  if (lane == 0) red[wid] = acc;
  __syncthreads();
  if (threadIdx.x == 0) partial[blockIdx.x] = red[0] + red[1] + red[2] + red[3];
}

__global__ __launch_bounds__(1024) void reduce_sum(
    const float* __restrict__ v, int n, float scale, float* __restrict__ out)
{
  __shared__ float red[1024];
  int tid = threadIdx.x;
  float a = 0.f;
  for (int i = tid; i < n; i += 1024) a += v[i];
  red[tid] = a; __syncthreads();
  for (int s = 512; s > 0; s >>= 1) { if (tid < s) red[tid] += red[tid + s]; __syncthreads(); }
  if (tid == 0) out[0] = red[0] * scale;
}

__global__ void copy_kernel(const float* __restrict__ src, float* __restrict__ dst, int n) {
  int i = blockIdx.x * blockDim.x + threadIdx.x;
  if (i < n) dst[i] = src[i];
}

__global__ void finalize(const float* __restrict__ parts, float* __restrict__ out) {
  if (threadIdx.x == 0)
    out[0] = parts[0] + parts[1] + parts[2] + parts[3] + parts[4] + parts[5] + parts[6];
}

// ---------------------------------------------------------------------------
extern "C" void kernel_launch(void* const* d_in, const int* in_sizes, int n_in,
                              void* d_out, int out_size, void* d_ws, size_t ws_size,
                              hipStream_t stream)
{
  const float* feat_P = (const float*)d_in[0];
  const float* feat_V = (const float*)d_in[1];
  const float* feat_C = (const float*)d_in[2];
  const float* feat_A = (const float*)d_in[3];
  const float* W1 = (const float*)d_in[4];
  const float* b1 = (const float*)d_in[5];
  const float* W2 = (const float*)d_in[6];
  const float* b2 = (const float*)d_in[7];
  const float* W3 = (const float*)d_in[8];
  const float* b3 = (const float*)d_in[9];
  const float* L00W = (const float*)d_in[10];
  const float* L00b = (const float*)d_in[11];
  const float* L01W = (const float*)d_in[12];
  const float* L01b = (const float*)d_in[13];
  const float* L10W = (const float*)d_in[14];
  const float* L10b = (const float*)d_in[15];
  const float* L11W = (const float*)d_in[16];
  const float* L11b = (const float*)d_in[17];
  const float* L12W = (const float*)d_in[18];
  const float* L12b = (const float*)d_in[19];
  const float* g0_Wih = (const float*)d_in[20];
  const float* g0_Whh = (const float*)d_in[21];
  const float* g0_bih = (const float*)d_in[22];
  const float* g0_bhh = (const float*)d_in[23];
  const float* g1_Wih = (const float*)d_in[24];
  const float* g1_Whh = (const float*)d_in[25];
  const float* g1_bih = (const float*)d_in[26];
  const float* g1_bhh = (const float*)d_in[27];
  const float* rel_emb = (const float*)d_in[28];
  const float* adj00 = (const float*)d_in[29];
  const float* adj01 = (const float*)d_in[30];
  const float* adj10 = (const float*)d_in[31];
  const float* adj11 = (const float*)d_in[32];
  const float* adj12 = (const float*)d_in[33];
  const float* clsA = (const float*)d_in[34];
  const float* clsP = (const float*)d_in[35];
  const float* clsV = (const float*)d_in[36];
  const int* u_s = (const int*)d_in[37];
  const int* u_d = (const int*)d_in[38];

  float* out = (float*)d_out;
  float* fe = out + 1;                          // final_ent [18500,128]
  float* rel_out = out + 1 + 18500 * 128;       // rel_emb copy [12,128]

  float* ws = (float*)d_ws;
  size_t o = 0;
  auto alloc = [&](size_t n) { float* p = ws + o; o += n; return p; };
  float* selfP = alloc(8000 * 128);
  float* selfV = alloc(3000 * 128);
  float* selfC = alloc(1500 * 128);
  float* selfA = alloc(6000 * 128);
  float* gi = alloc(8000 * 384);
  float* gh = alloc(8000 * 384);
  float* logits = alloc((size_t)8000 * 1500);
  float* scaled = alloc(8000 * 128);
  float* hbuf = alloc(8000 * 128);
  float* stP0 = alloc(8000 * 128);
  float* stA0 = alloc(6000 * 128);
  float* stP1 = alloc(8000 * 128);
  float* stV1 = alloc(3000 * 128);
  float* stC1 = alloc(1500 * 128);
  float* cebuf = alloc(8000);
  float* s0b = alloc(8000);
  float* s1b = alloc(8000);
  float* den = alloc(4);
  float* partial = alloc(1024);
  float* parts = alloc(8);
  (void)ws_size; (void)in_sizes; (void)n_in; (void)out_size;

  dim3 blk(256);
  auto gemm = [&](const float* X, const float* W, const float* b, float* C, int N, int O) {
    dim3 g((N + 127) / 128, (O + 127) / 128);
    hipLaunchKernelGGL(gemm_xwt, g, blk, 0, stream, X, W, b, C, N, O);
  };

  // self embeddings (independent of chain)
  gemm(feat_P, W1, b1, selfP, 8000, 128);
  gemm(feat_V, W1, b1, selfV, 3000, 128);
  gemm(feat_C, W1, b1, selfC, 1500, 128);
  gemm(feat_A, W1, b1, selfA, 6000, 128);

  auto run_stage = [&](int sidx, const float* xlog, int Nl,
                       const float* LW, const float* Lb, const float* cls,
                       const float* adj, int M,
                       const float* xfeat, const float* Wih, const float* bih,
                       const float* Whh, const float* bhh, float* state) {
    gemm(xlog, LW, Lb, logits, Nl, 1500);
    hipLaunchKernelGGL(rowops_kernel, dim3(Nl), blk, 0, stream, logits, cls, xlog, scaled, cebuf, Nl);
    hipLaunchKernelGGL(reduce_sum, dim3(1), dim3(1024), 0, stream, cebuf, Nl, -1.0f / (float)Nl, parts + sidx);
    hipLaunchKernelGGL(spmv_scan, dim3(M), blk, 0, stream, adj, scaled, hbuf, M, Nl);
    gemm(xfeat, Wih, bih, gi, M, 384);
    gemm(hbuf, Whh, bhh, gh, M, 384);
    hipLaunchKernelGGL(gru_elem, dim3((M * 128 + 255) / 256), blk, 0, stream, gi, gh, hbuf, state, M);
  };

  run_stage(0, feat_V, 3000, L00W, L00b, clsV, adj00, 8000, feat_P, g0_Wih, g0_bih, g0_Whh, g0_bhh, stP0);
  run_stage(1, stP0, 8000, L01W, L01b, clsP, adj01, 6000, feat_A, g0_Wih, g0_bih, g0_Whh, g0_bhh, stA0);
  run_stage(2, feat_A, 6000, L10W, L10b, clsA, adj10, 8000, feat_P, g1_Wih, g1_bih, g1_Whh, g1_bhh, stP1);
  run_stage(3, stP1, 8000, L11W, L11b, clsP, adj11, 3000, feat_V, g1_Wih, g1_bih, g1_Whh, g1_bhh, stV1);
  run_stage(4, stV1, 3000, L12W, L12b, clsV, adj12, 1500, feat_C, g1_Wih, g1_bih, g1_Whh, g1_bhh, stC1);

  auto fuse = [&](const float* e0, const float* e1, int N, int off) {
    hipLaunchKernelGGL(fuse_scores, dim3((N + 3) / 4), blk, 0, stream, e0, e1, W2, b2, W3, b3, s0b, s1b, N);
    hipLaunchKernelGGL(softmax_denom, dim3(1), dim3(1024), 0, stream, s0b, s1b, den, N);
    hipLaunchKernelGGL(fuse_emb, dim3((N * 128 + 255) / 256), blk, 0, stream, e0, e1, s0b, s1b, den,
                       fe + (size_t)off * 128, N);
  };
  fuse(selfP, stP0, 8000, 0);
  fuse(selfV, stV1, 3000, 8000);
  fuse(selfC, stC1, 1500, 11000);
  fuse(selfA, stA0, 6000, 12500);

  hipLaunchKernelGGL(copy_kernel, dim3(6), blk, 0, stream, rel_emb, rel_out, 12 * 128);

  hipLaunchKernelGGL(edge_d_kernel, dim3(1024), blk, 0, stream, u_d, fe, rel_emb, partial, 150000);
  hipLaunchKernelGGL(reduce_sum, dim3(1), dim3(1024), 0, stream, partial, 1024, 1.0f, parts + 5);
  hipLaunchKernelGGL(edge_s_kernel, dim3(1024), blk, 0, stream, u_s, fe, partial, 150000);
  hipLaunchKernelGGL(reduce_sum, dim3(1), dim3(1024), 0, stream, partial, 1024, 1.0f, parts + 6);

  hipLaunchKernelGGL(finalize, dim3(1), dim3(1), 0, stream, parts, out);
}

// Round 2
// 1074.512 us; speedup vs baseline: 23.1373x; 23.1373x over previous
//
#include <hip/hip_runtime.h>
#include <cstdint>
#include <cstddef>

#define DEV_INLINE __device__ __forceinline__

// ---------------------------------------------------------------------------
// Generic GEMM: C[N,O] = X[N,128] @ W[O,128]^T + bias[O]
// 64x64 tile, K=128 single pass, 4x4 micro-tile (acc=16 regs -> no spill),
// float4-granular XOR-swizzled LDS: idx = row*32 + (s ^ (row>>2)).
// ---------------------------------------------------------------------------
__global__ __launch_bounds__(256) void gemm_xwt(
    const float* __restrict__ X, const float* __restrict__ W,
    const float* __restrict__ bias, float* __restrict__ C,
    int N, int O)
{
  __shared__ float4 Xs[64 * 32];
  __shared__ float4 Ws[64 * 32];
  const int tid = threadIdx.x;
  const int tm = tid >> 4;   // 0..15
  const int tn = tid & 15;   // 0..15
  const int bm = blockIdx.x * 64;
  const int bn = blockIdx.y * 64;

  // stage both tiles: 64 rows x 32 float4 (full K=128) each
#pragma unroll
  for (int w = 0; w < 8; ++w) {
    int slot = tid + 256 * w;     // 0..2047
    int row = slot >> 5;          // 0..63
    int s = slot & 31;            // 0..31
    int idx = row * 32 + (s ^ (row >> 2));
    int gr = bm + row;
    float4 xv = make_float4(0.f, 0.f, 0.f, 0.f);
    if (gr < N) xv = *reinterpret_cast<const float4*>(X + (size_t)gr * 128 + s * 4);
    Xs[idx] = xv;
    int gw = bn + row;
    float4 wv = make_float4(0.f, 0.f, 0.f, 0.f);
    if (gw < O) wv = *reinterpret_cast<const float4*>(W + (size_t)gw * 128 + s * 4);
    Ws[idx] = wv;
  }
  __syncthreads();

  float acc[4][4];
#pragma unroll
  for (int i = 0; i < 4; ++i)
#pragma unroll
    for (int j = 0; j < 4; ++j) acc[i][j] = 0.f;

#pragma unroll 4
  for (int k4 = 0; k4 < 32; ++k4) {
    float4 xr[4], wr[4];
#pragma unroll
    for (int i = 0; i < 4; ++i) xr[i] = Xs[(tm * 4 + i) * 32 + (k4 ^ tm)];
#pragma unroll
    for (int j = 0; j < 4; ++j) wr[j] = Ws[(tn * 4 + j) * 32 + (k4 ^ tn)];
#pragma unroll
    for (int i = 0; i < 4; ++i)
#pragma unroll
      for (int j = 0; j < 4; ++j)
        acc[i][j] += xr[i].x * wr[j].x + xr[i].y * wr[j].y +
                     xr[i].z * wr[j].z + xr[i].w * wr[j].w;
  }

  // store: rows bm+tm*4+i, cols bn+tn*4..+3 contiguous -> float4
  // (O in {128,384,1500} all %4==0; row stride O*4 bytes is 16B-aligned)
#pragma unroll
  for (int i = 0; i < 4; ++i) {
    int r = bm + tm * 4 + i;
    int c = bn + tn * 4;
    if (r < N && c + 3 < O) {
      float4 o4 = make_float4(acc[i][0] + bias[c],
                              acc[i][1] + bias[c + 1],
                              acc[i][2] + bias[c + 2],
                              acc[i][3] + bias[c + 3]);
      *reinterpret_cast<float4*>(C + (size_t)r * O + c) = o4;
    }
  }
}

// ---------------------------------------------------------------------------
// Sparse row scan: H[M,128] = A[M,K] @ Xs[K,128], A is ~0.3% dense.
// One block (4 waves) per row; ballot over nonzeros; broadcast & accumulate.
// ---------------------------------------------------------------------------
__global__ __launch_bounds__(256) void spmv_scan(
    const float* __restrict__ A, const float* __restrict__ Xs,
    float* __restrict__ H, int M, int K)
{
  int row = blockIdx.x;
  int tid = threadIdx.x, wave = tid >> 6, lane = tid & 63;
  const float4* Arow = reinterpret_cast<const float4*>(A + (size_t)row * K);
  int K4 = K >> 2;  // K is always a multiple of 4 here
  float acc0 = 0.f, acc1 = 0.f;
  for (int base = wave * 64; base < K4; base += 256) {
    int q = base + lane;
    float4 a = (q < K4) ? Arow[q] : make_float4(0.f, 0.f, 0.f, 0.f);
#pragma unroll
    for (int c = 0; c < 4; ++c) {
      float av = (c == 0) ? a.x : (c == 1) ? a.y : (c == 2) ? a.z : a.w;
      unsigned long long mm = __ballot(av != 0.f);
      while (mm) {
        int b = __builtin_ctzll(mm);
        mm &= mm - 1;
        float v = __shfl(av, b);
        int jj = (base + b) * 4 + c;
        const float* xr = Xs + (size_t)jj * 128;
        acc0 += v * xr[lane];
        acc1 += v * xr[lane + 64];
      }
    }
  }
  __shared__ float red[4][128];
  red[wave][lane] = acc0;
  red[wave][lane + 64] = acc1;
  __syncthreads();
  if (wave == 0) {
    float r0 = red[0][lane] + red[1][lane] + red[2][lane] + red[3][lane];
    float r1 = red[0][lane + 64] + red[1][lane + 64] + red[2][lane + 64] + red[3][lane + 64];
    H[(size_t)row * 128 + lane] = r0;
    H[(size_t)row * 128 + 64 + lane] = r1;
  }
}

// ---------------------------------------------------------------------------
// Block reductions (blockDim.x == 256)
// ---------------------------------------------------------------------------
DEV_INLINE float br_max(float v, float* red) {
  int tid = threadIdx.x;
  red[tid] = v; __syncthreads();
#pragma unroll
  for (int s = 128; s > 0; s >>= 1) { if (tid < s) red[tid] = fmaxf(red[tid], red[tid + s]); __syncthreads(); }
  float r = red[0]; __syncthreads();
  return r;
}
DEV_INLINE float br_sum(float v, float* red) {
  int tid = threadIdx.x;
  red[tid] = v; __syncthreads();
#pragma unroll
  for (int s = 128; s > 0; s >>= 1) { if (tid < s) red[tid] += red[tid + s]; __syncthreads(); }
  float r = red[0]; __syncthreads();
  return r;
}

// ---------------------------------------------------------------------------
// Per-row: softmax(logits) -> p; tcp = <p, cls>; lsum = sum(cls);
// lse2 = log_softmax of p (softmax-of-softmax in the reference): max(p) = 1/Z1.
// ce[row] = tcp - lsum*(m2 + log Z2);   scaled[row,:] = tcp * src[row,:]
// ---------------------------------------------------------------------------
__global__ __launch_bounds__(256) void rowops_kernel(
    const float* __restrict__ logits, const float* __restrict__ cls,
    const float* __restrict__ src, float* __restrict__ scaled,
    float* __restrict__ ce, int N)
{
  __shared__ float ls[1500];
  __shared__ float red[256];
  __shared__ float tbc;
  int row = blockIdx.x;
  int tid = threadIdx.x;
  const float* lr = logits + (size_t)row * 1500;
  float m = -3.4e38f;
  for (int j = tid; j < 1500; j += 256) { float v = lr[j]; ls[j] = v; m = fmaxf(m, v); }
  float m1 = br_max(m, red);
  float z = 0.f;
  for (int j = tid; j < 1500; j += 256) { float e = expf(ls[j] - m1); ls[j] = e; z += e; }
  float Z1 = br_sum(z, red);
  float invZ1 = 1.0f / Z1;
  float m2 = invZ1;   // max(p) == exp(0)/Z1 exactly
  const float* cr = cls + (size_t)row * 1500;
  float t = 0.f, lsum = 0.f, z2 = 0.f;
  for (int j = tid; j < 1500; j += 256) {
    float p = ls[j] * invZ1;
    float c = cr[j];
    t += c * p; lsum += c; z2 += expf(p - m2);
  }
  t = br_sum(t, red);
  lsum = br_sum(lsum, red);
  z2 = br_sum(z2, red);
  if (tid == 0) { ce[row] = t - lsum * (m2 + logf(z2)); tbc = t; }
  __syncthreads();
  if (tid < 128) scaled[(size_t)row * 128 + tid] = tbc * src[(size_t)row * 128 + tid];
}

// ---------------------------------------------------------------------------
// GRU elementwise: gi/gh are [N,384] (ir|iz|in, hr|hz|hn), h is [N,128]
// ---------------------------------------------------------------------------
__global__ __launch_bounds__(256) void gru_elem(
    const float* __restrict__ gi, const float* __restrict__ gh,
    const float* __restrict__ h, float* __restrict__ out, int N)
{
  int idx = blockIdx.x * 256 + threadIdx.x;
  if (idx >= N * 128) return;
  int i = idx >> 7, d = idx & 127;
  const float* gir = gi + (size_t)i * 384;
  const float* ghr = gh + (size_t)i * 384;
  float ir = gir[d], iz = gir[128 + d], inn = gir[256 + d];
  float hr = ghr[d], hz = ghr[128 + d], hn = ghr[256 + d];
  float r = 1.f / (1.f + expf(-(ir + hr)));
  float zz = 1.f / (1.f + expf(-(iz + hz)));
  float n = tanhf(inn + r * hn);
  float hv = h[idx];
  out[idx] = (1.f - zz) * n + zz * hv;
}

// ---------------------------------------------------------------------------
// Fuse scores: s0[i] = relu(<e0[i],W2>+b2), s1[i] = relu(<e1[i],W3>+b3)
// one wave per row
// ---------------------------------------------------------------------------
__global__ __launch_bounds__(256) void fuse_scores(
    const float* __restrict__ e0, const float* __restrict__ e1,
    const float* __restrict__ W2, const float* __restrict__ b2,
    const float* __restrict__ W3, const float* __restrict__ b3,
    float* __restrict__ s0, float* __restrict__ s1, int N)
{
  int lane = threadIdx.x & 63;
  int wave = (blockIdx.x * 256 + threadIdx.x) >> 6;
  if (wave >= N) return;
  float a0 = e0[(size_t)wave * 128 + lane] * W2[lane] + e0[(size_t)wave * 128 + 64 + lane] * W2[64 + lane];
  float a1 = e1[(size_t)wave * 128 + lane] * W3[lane] + e1[(size_t)wave * 128 + 64 + lane] * W3[64 + lane];
#pragma unroll
  for (int o = 32; o > 0; o >>= 1) { a0 += __shfl_down(a0, o); a1 += __shfl_down(a1, o); }
  if (lane == 0) {
    s0[wave] = fmaxf(a0 + b2[0], 0.f);
    s1[wave] = fmaxf(a1 + b3[0], 0.f);
  }
}

// den[0..3] = {max(s0), sum exp(s0-max), max(s1), sum exp(s1-max)} -- softmax over NODE axis
__global__ __launch_bounds__(1024) void softmax_denom(
    const float* __restrict__ s0, const float* __restrict__ s1,
    float* __restrict__ den, int N)
{
  __shared__ float red[1024];
  int tid = threadIdx.x;
  float m = -3.4e38f;
  for (int i = tid; i < N; i += 1024) m = fmaxf(m, s0[i]);
  red[tid] = m; __syncthreads();
  for (int s = 512; s > 0; s >>= 1) { if (tid < s) red[tid] = fmaxf(red[tid], red[tid + s]); __syncthreads(); }
  float m0 = red[0]; __syncthreads();
  float z = 0.f;
  for (int i = tid; i < N; i += 1024) z += expf(s0[i] - m0);
  red[tid] = z; __syncthreads();
  for (int s = 512; s > 0; s >>= 1) { if (tid < s) red[tid] += red[tid + s]; __syncthreads(); }
  float Z0 = red[0]; __syncthreads();
  m = -3.4e38f;
  for (int i = tid; i < N; i += 1024) m = fmaxf(m, s1[i]);
  red[tid] = m; __syncthreads();
  for (int s = 512; s > 0; s >>= 1) { if (tid < s) red[tid] = fmaxf(red[tid], red[tid + s]); __syncthreads(); }
  float m1 = red[0]; __syncthreads();
  z = 0.f;
  for (int i = tid; i < N; i += 1024) z += expf(s1[i] - m1);
  red[tid] = z; __syncthreads();
  for (int s = 512; s > 0; s >>= 1) { if (tid < s) red[tid] += red[tid + s]; __syncthreads(); }
  if (tid == 0) { den[0] = m0; den[1] = Z0; den[2] = m1; den[3] = red[0]; }
}

__global__ __launch_bounds__(256) void fuse_emb(
    const float* __restrict__ e0, const float* __restrict__ e1,
    const float* __restrict__ s0, const float* __restrict__ s1,
    const float* __restrict__ den, float* __restrict__ out, int N)
{
  int idx = blockIdx.x * 256 + threadIdx.x;
  if (idx >= N * 128) return;
  int i = idx >> 7;
  float a0 = expf(s0[i] - den[0]) / den[1];
  float a1 = expf(s1[i] - den[2]) / den[3];
  out[idx] = fmaxf(a0 * e0[idx] + a1 * e1[idx], 0.f);
}

// ---------------------------------------------------------------------------
// Edge losses: accumulate -log_sigmoid terms into per-block partials (deterministic)
// ---------------------------------------------------------------------------
__global__ __launch_bounds__(256) void edge_d_kernel(
    const int* __restrict__ ud, const float* __restrict__ fe,
    const float* __restrict__ rel, float* __restrict__ partial, int En)
{
  int lane = threadIdx.x & 63;
  int wid = threadIdx.x >> 6;
  int gw = blockIdx.x * 4 + wid;
  int nw = gridDim.x * 4;
  float acc = 0.f;
  for (int e = gw; e < En; e += nw) {
    int4 ei = *reinterpret_cast<const int4*>(ud + (size_t)e * 4);
    const float* fi = fe + (size_t)ei.x * 128;
    const float* fj = fe + (size_t)ei.y * 128;
    const float* rr = rel + (size_t)ei.w * 128;
    float t0 = tanhf(fi[lane] + fj[lane]);
    float t1 = tanhf(fi[lane + 64] + fj[lane + 64]);
    float d = rr[lane] * t0 + rr[lane + 64] * t1;
#pragma unroll
    for (int o = 32; o > 0; o >>= 1) d += __shfl_down(d, o);
    if (lane == 0) {
      float x = (float)ei.z * d;
      acc += (x >= 0.f) ? log1pf(expf(-x)) : (-x + log1pf(expf(x)));
    }
  }
  __shared__ float red[4];
  if (lane == 0) red[wid] = acc;
  __syncthreads();
  if (threadIdx.x == 0) partial[blockIdx.x] = red[0] + red[1] + red[2] + red[3];
}

__global__ __launch_bounds__(256) void edge_s_kernel(
    const int* __restrict__ us, const float* __restrict__ fe,
    float* __restrict__ partial, int En)
{
  int lane = threadIdx.x & 63;
  int wid = threadIdx.x >> 6;
  int gw = blockIdx.x * 4 + wid;
  int nw = gridDim.x * 4;
  float acc = 0.f;
  for (int e = gw; e < En; e += nw) {
    int i = us[(size_t)e * 3], j = us[(size_t)e * 3 + 1], lab = us[(size_t)e * 3 + 2];
    const float* fi = fe + (size_t)i * 128;
    const float* fj = fe + (size_t)j * 128;
    float d = fi[lane] * fj[lane] + fi[lane + 64] * fj[lane + 64];
#pragma unroll
    for (int o = 32; o > 0; o >>= 1) d += __shfl_down(d, o);
    if (lane == 0) {
      float x = (float)lab * d;
      acc += (x >= 0.f) ? log1pf(expf(-x)) : (-x + log1pf(expf(x)));
    }
  }
  __shared__ float red[4];
  if (lane == 0) red[wid] = acc;
  __syncthreads();
  if (threadIdx.x == 0) partial[blockIdx.x] = red[0] + red[1] + red[2] + red[3];
}

__global__ __launch_bounds__(1024) void reduce_sum(
    const float* __restrict__ v, int n, float scale, float* __restrict__ out)
{
  __shared__ float red[1024];
  int tid = threadIdx.x;
  float a = 0.f;
  for (int i = tid; i < n; i += 1024) a += v[i];
  red[tid] = a; __syncthreads();
  for (int s = 512; s > 0; s >>= 1) { if (tid < s) red[tid] += red[tid + s]; __syncthreads(); }
  if (tid == 0) out[0] = red[0] * scale;
}

__global__ void copy_kernel(const float* __restrict__ src, float* __restrict__ dst, int n) {
  int i = blockIdx.x * blockDim.x + threadIdx.x;
  if (i < n) dst[i] = src[i];
}

__global__ void finalize(const float* __restrict__ parts, float* __restrict__ out) {
  if (threadIdx.x == 0)
    out[0] = parts[0] + parts[1] + parts[2] + parts[3] + parts[4] + parts[5] + parts[6];
}

// ---------------------------------------------------------------------------
extern "C" void kernel_launch(void* const* d_in, const int* in_sizes, int n_in,
                              void* d_out, int out_size, void* d_ws, size_t ws_size,
                              hipStream_t stream)
{
  const float* feat_P = (const float*)d_in[0];
  const float* feat_V = (const float*)d_in[1];
  const float* feat_C = (const float*)d_in[2];
  const float* feat_A = (const float*)d_in[3];
  const float* W1 = (const float*)d_in[4];
  const float* b1 = (const float*)d_in[5];
  const float* W2 = (const float*)d_in[6];
  const float* b2 = (const float*)d_in[7];
  const float* W3 = (const float*)d_in[8];
  const float* b3 = (const float*)d_in[9];
  const float* L00W = (const float*)d_in[10];
  const float* L00b = (const float*)d_in[11];
  const float* L01W = (const float*)d_in[12];
  const float* L01b = (const float*)d_in[13];
  const float* L10W = (const float*)d_in[14];
  const float* L10b = (const float*)d_in[15];
  const float* L11W = (const float*)d_in[16];
  const float* L11b = (const float*)d_in[17];
  const float* L12W = (const float*)d_in[18];
  const float* L12b = (const float*)d_in[19];
  const float* g0_Wih = (const float*)d_in[20];
  const float* g0_Whh = (const float*)d_in[21];
  const float* g0_bih = (const float*)d_in[22];
  const float* g0_bhh = (const float*)d_in[23];
  const float* g1_Wih = (const float*)d_in[24];
  const float* g1_Whh = (const float*)d_in[25];
  const float* g1_bih = (const float*)d_in[26];
  const float* g1_bhh = (const float*)d_in[27];
  const float* rel_emb = (const float*)d_in[28];
  const float* adj00 = (const float*)d_in[29];
  const float* adj01 = (const float*)d_in[30];
  const float* adj10 = (const float*)d_in[31];
  const float* adj11 = (const float*)d_in[32];
  const float* adj12 = (const float*)d_in[33];
  const float* clsA = (const float*)d_in[34];
  const float* clsP = (const float*)d_in[35];
  const float* clsV = (const float*)d_in[36];
  const int* u_s = (const int*)d_in[37];
  const int* u_d = (const int*)d_in[38];

  float* out = (float*)d_out;
  float* fe = out + 1;                          // final_ent [18500,128]
  float* rel_out = out + 1 + 18500 * 128;       // rel_emb copy [12,128]

  float* ws = (float*)d_ws;
  size_t o = 0;
  auto alloc = [&](size_t n) { float* p = ws + o; o += n; return p; };
  float* selfP = alloc(8000 * 128);
  float* selfV = alloc(3000 * 128);
  float* selfC = alloc(1500 * 128);
  float* selfA = alloc(6000 * 128);
  float* gi = alloc(8000 * 384);
  float* gh = alloc(8000 * 384);
  float* logits = alloc((size_t)8000 * 1500);
  float* scaled = alloc(8000 * 128);
  float* hbuf = alloc(8000 * 128);
  float* stP0 = alloc(8000 * 128);
  float* stA0 = alloc(6000 * 128);
  float* stP1 = alloc(8000 * 128);
  float* stV1 = alloc(3000 * 128);
  float* stC1 = alloc(1500 * 128);
  float* cebuf = alloc(8000);
  float* s0b = alloc(8000);
  float* s1b = alloc(8000);
  float* den = alloc(4);
  float* partial = alloc(1024);
  float* parts = alloc(8);
  (void)ws_size; (void)in_sizes; (void)n_in; (void)out_size;

  dim3 blk(256);
  auto gemm = [&](const float* X, const float* W, const float* b, float* C, int N, int O) {
    dim3 g((N + 63) / 64, (O + 63) / 64);
    hipLaunchKernelGGL(gemm_xwt, g, blk, 0, stream, X, W, b, C, N, O);
  };

  // self embeddings (independent of chain)
  gemm(feat_P, W1, b1, selfP, 8000, 128);
  gemm(feat_V, W1, b1, selfV, 3000, 128);
  gemm(feat_C, W1, b1, selfC, 1500, 128);
  gemm(feat_A, W1, b1, selfA, 6000, 128);

  auto run_stage = [&](int sidx, const float* xlog, int Nl,
                       const float* LW, const float* Lb, const float* cls,
                       const float* adj, int M,
                       const float* xfeat, const float* Wih, const float* bih,
                       const float* Whh, const float* bhh, float* state) {
    gemm(xlog, LW, Lb, logits, Nl, 1500);
    hipLaunchKernelGGL(rowops_kernel, dim3(Nl), blk, 0, stream, logits, cls, xlog, scaled, cebuf, Nl);
    hipLaunchKernelGGL(reduce_sum, dim3(1), dim3(1024), 0, stream, cebuf, Nl, -1.0f / (float)Nl, parts + sidx);
    hipLaunchKernelGGL(spmv_scan, dim3(M), blk, 0, stream, adj, scaled, hbuf, M, Nl);
    gemm(xfeat, Wih, bih, gi, M, 384);
    gemm(hbuf, Whh, bhh, gh, M, 384);
    hipLaunchKernelGGL(gru_elem, dim3((M * 128 + 255) / 256), blk, 0, stream, gi, gh, hbuf, state, M);
  };

  run_stage(0, feat_V, 3000, L00W, L00b, clsV, adj00, 8000, feat_P, g0_Wih, g0_bih, g0_Whh, g0_bhh, stP0);
  run_stage(1, stP0, 8000, L01W, L01b, clsP, adj01, 6000, feat_A, g0_Wih, g0_bih, g0_Whh, g0_bhh, stA0);
  run_stage(2, feat_A, 6000, L10W, L10b, clsA, adj10, 8000, feat_P, g1_Wih, g1_bih, g1_Whh, g1_bhh, stP1);
  run_stage(3, stP1, 8000, L11W, L11b, clsP, adj11, 3000, feat_V, g1_Wih, g1_bih, g1_Whh, g1_bhh, stV1);
  run_stage(4, stV1, 3000, L12W, L12b, clsV, adj12, 1500, feat_C, g1_Wih, g1_bih, g1_Whh, g1_bhh, stC1);

  auto fuse = [&](const float* e0, const float* e1, int N, int off) {
    hipLaunchKernelGGL(fuse_scores, dim3((N + 3) / 4), blk, 0, stream, e0, e1, W2, b2, W3, b3, s0b, s1b, N);
    hipLaunchKernelGGL(softmax_denom, dim3(1), dim3(1024), 0, stream, s0b, s1b, den, N);
    hipLaunchKernelGGL(fuse_emb, dim3((N * 128 + 255) / 256), blk, 0, stream, e0, e1, s0b, s1b, den,
                       fe + (size_t)off * 128, N);
  };
  fuse(selfP, stP0, 8000, 0);
  fuse(selfV, stV1, 3000, 8000);
  fuse(selfC, stC1, 1500, 11000);
  fuse(selfA, stA0, 6000, 12500);

  hipLaunchKernelGGL(copy_kernel, dim3(6), blk, 0, stream, rel_emb, rel_out, 12 * 128);

  hipLaunchKernelGGL(edge_d_kernel, dim3(1024), blk, 0, stream, u_d, fe, rel_emb, partial, 150000);
  hipLaunchKernelGGL(reduce_sum, dim3(1), dim3(1024), 0, stream, partial, 1024, 1.0f, parts + 5);
  hipLaunchKernelGGL(edge_s_kernel, dim3(1024), blk, 0, stream, u_s, fe, partial, 150000);
  hipLaunchKernelGGL(reduce_sum, dim3(1), dim3(1024), 0, stream, partial, 1024, 1.0f, parts + 6);

  hipLaunchKernelGGL(finalize, dim3(1), dim3(1), 0, stream, parts, out);
}

// Round 3
// 746.626 us; speedup vs baseline: 33.2983x; 1.4392x over previous
//
#include <hip/hip_runtime.h>
#include <cstdint>
#include <cstddef>

#define DEV_INLINE __device__ __forceinline__

typedef __attribute__((ext_vector_type(8))) short bf16x8;
typedef __attribute__((ext_vector_type(16))) float f32x16;
struct __align__(8) US4 { unsigned short u[4]; };

DEV_INLINE unsigned short f2bf(float x) {
  unsigned u = __float_as_uint(x);
  return (unsigned short)((u + 0x7FFFu + ((u >> 16) & 1u)) >> 16);
}

// ---------------------------------------------------------------------------
// Batched f32 -> bf16 conversion (one launch for feats + all weights)
// ---------------------------------------------------------------------------
struct CvtSeg { const float* src; unsigned short* dst; int n; int nblk; };
struct CvtArgs { CvtSeg seg[16]; int nseg; };

__global__ __launch_bounds__(256) void convert_bf16_many(CvtArgs args) {
  int b = blockIdx.x;
  int s = 0;
  while (s < args.nseg && b >= args.seg[s].nblk) { b -= args.seg[s].nblk; ++s; }
  if (s >= args.nseg) return;
  int base = b * 1024 + threadIdx.x * 4;
  if (base >= args.seg[s].n) return;
  float4 v = *reinterpret_cast<const float4*>(args.seg[s].src + base);
  US4 o;
  o.u[0] = f2bf(v.x); o.u[1] = f2bf(v.y); o.u[2] = f2bf(v.z); o.u[3] = f2bf(v.w);
  *reinterpret_cast<US4*>(args.seg[s].dst + base) = o;
}

// ---------------------------------------------------------------------------
// bf16 MFMA GEMM: C[N,O] = Xb[N,128] @ Wb[O,128]^T + bias[O]   (f32 accum/out)
// Block 256 thr = 4 waves; tile 128(M)x64(N); wave w -> rows w*32..w*32+31,
// 2 col-subtiles of 32 via mfma_f32_32x32x16_bf16, 8 K-steps of 16.
// LDS bf16 tiles XOR-swizzled (c16 ^ (row&7)) for conflict-reduced b128 reads.
// ---------------------------------------------------------------------------
__global__ __launch_bounds__(256) void gemm_bf16(
    const unsigned short* __restrict__ Xb, const unsigned short* __restrict__ Wb,
    const float* __restrict__ bias, float* __restrict__ C, int N, int O)
{
  __shared__ __align__(16) unsigned short Xs[128 * 128];  // 32 KB
  __shared__ __align__(16) unsigned short Ws[64 * 128];   // 16 KB
  const int tid = threadIdx.x;
  const int bm = blockIdx.x * 128;
  const int bn = blockIdx.y * 64;

#pragma unroll
  for (int i = 0; i < 8; ++i) {
    int s = tid + 256 * i;           // 0..2047
    int row = s >> 4, c16 = s & 15;
    uint4 v = make_uint4(0, 0, 0, 0);
    int gr = bm + row;
    if (gr < N) v = *reinterpret_cast<const uint4*>(Xb + (size_t)gr * 128 + c16 * 8);
    *reinterpret_cast<uint4*>(&Xs[(row * 16 + (c16 ^ (row & 7))) * 8]) = v;
  }
#pragma unroll
  for (int i = 0; i < 4; ++i) {
    int s = tid + 256 * i;           // 0..1023
    int row = s >> 4, c16 = s & 15;
    uint4 v = make_uint4(0, 0, 0, 0);
    int gw = bn + row;
    if (gw < O) v = *reinterpret_cast<const uint4*>(Wb + (size_t)gw * 128 + c16 * 8);
    *reinterpret_cast<uint4*>(&Ws[(row * 16 + (c16 ^ (row & 7))) * 8]) = v;
  }
  __syncthreads();

  const int wave = tid >> 6, lane = tid & 63;
  const int l31 = lane & 31, lhi = lane >> 5;

  f32x16 acc0, acc1;
#pragma unroll
  for (int i = 0; i < 16; ++i) { acc0[i] = 0.f; acc1[i] = 0.f; }

  const int ar = wave * 32 + l31;
#pragma unroll
  for (int ks = 0; ks < 8; ++ks) {
    int c16 = ks * 2 + lhi;
    bf16x8 a  = *reinterpret_cast<const bf16x8*>(&Xs[(ar * 16 + (c16 ^ (ar & 7))) * 8]);
    bf16x8 b0 = *reinterpret_cast<const bf16x8*>(&Ws[(l31 * 16 + (c16 ^ (l31 & 7))) * 8]);
    int br1 = 32 + l31;
    bf16x8 b1 = *reinterpret_cast<const bf16x8*>(&Ws[(br1 * 16 + (c16 ^ (br1 & 7))) * 8]);
    acc0 = __builtin_amdgcn_mfma_f32_32x32x16_bf16(a, b0, acc0, 0, 0, 0);
    acc1 = __builtin_amdgcn_mfma_f32_32x32x16_bf16(a, b1, acc1, 0, 0, 0);
  }

  // C/D layout: col = lane&31, row = (reg&3) + 8*(reg>>2) + 4*(lane>>5)
#pragma unroll
  for (int reg = 0; reg < 16; ++reg) {
    int r = bm + wave * 32 + (reg & 3) + 8 * (reg >> 2) + 4 * lhi;
    if (r < N) {
      int c0 = bn + l31;
      if (c0 < O) C[(size_t)r * O + c0] = acc0[reg] + bias[c0];
      int c1 = bn + 32 + l31;
      if (c1 < O) C[(size_t)r * O + c1] = acc1[reg] + bias[c1];
    }
  }
}

// ---------------------------------------------------------------------------
// Sparse row scan: H[M,128] = A[M,K] @ Xs[K,128]; also emits bf16 copy of H.
// ---------------------------------------------------------------------------
__global__ __launch_bounds__(256) void spmv_scan(
    const float* __restrict__ A, const float* __restrict__ Xs,
    float* __restrict__ H, unsigned short* __restrict__ Hb, int M, int K)
{
  int row = blockIdx.x;
  int tid = threadIdx.x, wave = tid >> 6, lane = tid & 63;
  const float4* Arow = reinterpret_cast<const float4*>(A + (size_t)row * K);
  int K4 = K >> 2;
  float acc0 = 0.f, acc1 = 0.f;
  for (int base = wave * 64; base < K4; base += 256) {
    int q = base + lane;
    float4 a = (q < K4) ? Arow[q] : make_float4(0.f, 0.f, 0.f, 0.f);
#pragma unroll
    for (int c = 0; c < 4; ++c) {
      float av = (c == 0) ? a.x : (c == 1) ? a.y : (c == 2) ? a.z : a.w;
      unsigned long long mm = __ballot(av != 0.f);
      while (mm) {
        int b = __builtin_ctzll(mm);
        mm &= mm - 1;
        float v = __shfl(av, b);
        int jj = (base + b) * 4 + c;
        const float* xr = Xs + (size_t)jj * 128;
        acc0 += v * xr[lane];
        acc1 += v * xr[lane + 64];
      }
    }
  }
  __shared__ float red[4][128];
  red[wave][lane] = acc0;
  red[wave][lane + 64] = acc1;
  __syncthreads();
  if (wave == 0) {
    float r0 = red[0][lane] + red[1][lane] + red[2][lane] + red[3][lane];
    float r1 = red[0][lane + 64] + red[1][lane + 64] + red[2][lane + 64] + red[3][lane + 64];
    H[(size_t)row * 128 + lane] = r0;
    H[(size_t)row * 128 + 64 + lane] = r1;
    Hb[(size_t)row * 128 + lane] = f2bf(r0);
    Hb[(size_t)row * 128 + 64 + lane] = f2bf(r1);
  }
}

// ---------------------------------------------------------------------------
DEV_INLINE float br_max(float v, float* red) {
  int tid = threadIdx.x;
  red[tid] = v; __syncthreads();
#pragma unroll
  for (int s = 128; s > 0; s >>= 1) { if (tid < s) red[tid] = fmaxf(red[tid], red[tid + s]); __syncthreads(); }
  float r = red[0]; __syncthreads();
  return r;
}
DEV_INLINE float br_sum(float v, float* red) {
  int tid = threadIdx.x;
  red[tid] = v; __syncthreads();
#pragma unroll
  for (int s = 128; s > 0; s >>= 1) { if (tid < s) red[tid] += red[tid + s]; __syncthreads(); }
  float r = red[0]; __syncthreads();
  return r;
}

// ---------------------------------------------------------------------------
// Per-row softmax / CE (softmax-of-softmax, max(p)=1/Z1) / tcp scaling.
// ---------------------------------------------------------------------------
__global__ __launch_bounds__(256) void rowops_kernel(
    const float* __restrict__ logits, const float* __restrict__ cls,
    const float* __restrict__ src, float* __restrict__ scaled,
    float* __restrict__ ce, int N)
{
  __shared__ float ls[1500];
  __shared__ float red[256];
  __shared__ float tbc;
  int row = blockIdx.x;
  int tid = threadIdx.x;
  const float4* lr4 = reinterpret_cast<const float4*>(logits + (size_t)row * 1500);
  float m = -3.4e38f;
  for (int j = tid; j < 375; j += 256) {
    float4 v = lr4[j];
    *reinterpret_cast<float4*>(&ls[j * 4]) = v;
    m = fmaxf(fmaxf(m, fmaxf(v.x, v.y)), fmaxf(v.z, v.w));
  }
  float m1 = br_max(m, red);
  float z = 0.f;
  for (int j = tid; j < 375; j += 256) {
    float4 v = *reinterpret_cast<float4*>(&ls[j * 4]);
    v.x = expf(v.x - m1); v.y = expf(v.y - m1);
    v.z = expf(v.z - m1); v.w = expf(v.w - m1);
    *reinterpret_cast<float4*>(&ls[j * 4]) = v;
    z += (v.x + v.y) + (v.z + v.w);
  }
  float Z1 = br_sum(z, red);
  float invZ1 = 1.0f / Z1;
  float m2 = invZ1;  // max(p) == 1/Z1 exactly
  const float4* cr4 = reinterpret_cast<const float4*>(cls + (size_t)row * 1500);
  float t = 0.f, lsum = 0.f, z2 = 0.f;
  for (int j = tid; j < 375; j += 256) {
    float4 p = *reinterpret_cast<float4*>(&ls[j * 4]);
    float4 c = cr4[j];
    p.x *= invZ1; p.y *= invZ1; p.z *= invZ1; p.w *= invZ1;
    t += c.x * p.x + c.y * p.y + c.z * p.z + c.w * p.w;
    lsum += (c.x + c.y) + (c.z + c.w);
    z2 += expf(p.x - m2) + expf(p.y - m2) + expf(p.z - m2) + expf(p.w - m2);
  }
  t = br_sum(t, red);
  lsum = br_sum(lsum, red);
  z2 = br_sum(z2, red);
  if (tid == 0) { ce[row] = t - lsum * (m2 + logf(z2)); tbc = t; }
  __syncthreads();
  if (tid < 128) scaled[(size_t)row * 128 + tid] = tbc * src[(size_t)row * 128 + tid];
}

// ce partials for all 5 stages in one launch: parts[b] = -mean(cebuf[b*8000..])
__global__ __launch_bounds__(256) void ce_reduce5(
    const float* __restrict__ cebuf, float* __restrict__ parts)
{
  __shared__ float red[256];
  const int ns[5] = {3000, 8000, 6000, 8000, 3000};
  int b = blockIdx.x;
  int n = ns[b];
  const float* v = cebuf + b * 8000;
  int tid = threadIdx.x;
  float a = 0.f;
  for (int i = tid; i < n; i += 256) a += v[i];
  float s = br_sum(a, red);
  if (tid == 0) parts[b] = -s / (float)n;
}

// ---------------------------------------------------------------------------
// GRU elementwise, 4 elems/thread; emits f32 state + bf16 copy.
// ---------------------------------------------------------------------------
__global__ __launch_bounds__(256) void gru_elem(
    const float* __restrict__ gi, const float* __restrict__ gh,
    const float* __restrict__ h, float* __restrict__ out,
    unsigned short* __restrict__ outb, int N)
{
  int q = blockIdx.x * 256 + threadIdx.x;
  if (q >= N * 32) return;
  int i = q >> 5, d4 = (q & 31) * 4;
  const float* gir = gi + (size_t)i * 384;
  const float* ghr = gh + (size_t)i * 384;
  float4 ir4 = *reinterpret_cast<const float4*>(gir + d4);
  float4 iz4 = *reinterpret_cast<const float4*>(gir + 128 + d4);
  float4 in4 = *reinterpret_cast<const float4*>(gir + 256 + d4);
  float4 hr4 = *reinterpret_cast<const float4*>(ghr + d4);
  float4 hz4 = *reinterpret_cast<const float4*>(ghr + 128 + d4);
  float4 hn4 = *reinterpret_cast<const float4*>(ghr + 256 + d4);
  float4 hv4 = *reinterpret_cast<const float4*>(h + (size_t)i * 128 + d4);
  float4 o4;
  {
    float r = 1.f / (1.f + expf(-(ir4.x + hr4.x)));
    float zz = 1.f / (1.f + expf(-(iz4.x + hz4.x)));
    float n = tanhf(in4.x + r * hn4.x);
    o4.x = (1.f - zz) * n + zz * hv4.x;
  }
  {
    float r = 1.f / (1.f + expf(-(ir4.y + hr4.y)));
    float zz = 1.f / (1.f + expf(-(iz4.y + hz4.y)));
    float n = tanhf(in4.y + r * hn4.y);
    o4.y = (1.f - zz) * n + zz * hv4.y;
  }
  {
    float r = 1.f / (1.f + expf(-(ir4.z + hr4.z)));
    float zz = 1.f / (1.f + expf(-(iz4.z + hz4.z)));
    float n = tanhf(in4.z + r * hn4.z);
    o4.z = (1.f - zz) * n + zz * hv4.z;
  }
  {
    float r = 1.f / (1.f + expf(-(ir4.w + hr4.w)));
    float zz = 1.f / (1.f + expf(-(iz4.w + hz4.w)));
    float n = tanhf(in4.w + r * hn4.w);
    o4.w = (1.f - zz) * n + zz * hv4.w;
  }
  *reinterpret_cast<float4*>(out + (size_t)i * 128 + d4) = o4;
  US4 ob;
  ob.u[0] = f2bf(o4.x); ob.u[1] = f2bf(o4.y); ob.u[2] = f2bf(o4.z); ob.u[3] = f2bf(o4.w);
  *reinterpret_cast<US4*>(outb + (size_t)i * 128 + d4) = ob;
}

// ---------------------------------------------------------------------------
__global__ __launch_bounds__(256) void fuse_scores(
    const float* __restrict__ e0, const float* __restrict__ e1,
    const float* __restrict__ W2, const float* __restrict__ b2,
    const float* __restrict__ W3, const float* __restrict__ b3,
    float* __restrict__ s0, float* __restrict__ s1, int N)
{
  int lane = threadIdx.x & 63;
  int wave = (blockIdx.x * 256 + threadIdx.x) >> 6;
  if (wave >= N) return;
  float a0 = e0[(size_t)wave * 128 + lane] * W2[lane] + e0[(size_t)wave * 128 + 64 + lane] * W2[64 + lane];
  float a1 = e1[(size_t)wave * 128 + lane] * W3[lane] + e1[(size_t)wave * 128 + 64 + lane] * W3[64 + lane];
#pragma unroll
  for (int o = 32; o > 0; o >>= 1) { a0 += __shfl_down(a0, o); a1 += __shfl_down(a1, o); }
  if (lane == 0) {
    s0[wave] = fmaxf(a0 + b2[0], 0.f);
    s1[wave] = fmaxf(a1 + b3[0], 0.f);
  }
}

__global__ __launch_bounds__(1024) void softmax_denom(
    const float* __restrict__ s0, const float* __restrict__ s1,
    float* __restrict__ den, int N)
{
  __shared__ float red[1024];
  int tid = threadIdx.x;
  float m = -3.4e38f;
  for (int i = tid; i < N; i += 1024) m = fmaxf(m, s0[i]);
  red[tid] = m; __syncthreads();
  for (int s = 512; s > 0; s >>= 1) { if (tid < s) red[tid] = fmaxf(red[tid], red[tid + s]); __syncthreads(); }
  float m0 = red[0]; __syncthreads();
  float z = 0.f;
  for (int i = tid; i < N; i += 1024) z += expf(s0[i] - m0);
  red[tid] = z; __syncthreads();
  for (int s = 512; s > 0; s >>= 1) { if (tid < s) red[tid] += red[tid + s]; __syncthreads(); }
  float Z0 = red[0]; __syncthreads();
  m = -3.4e38f;
  for (int i = tid; i < N; i += 1024) m = fmaxf(m, s1[i]);
  red[tid] = m; __syncthreads();
  for (int s = 512; s > 0; s >>= 1) { if (tid < s) red[tid] = fmaxf(red[tid], red[tid + s]); __syncthreads(); }
  float m1 = red[0]; __syncthreads();
  z = 0.f;
  for (int i = tid; i < N; i += 1024) z += expf(s1[i] - m1);
  red[tid] = z; __syncthreads();
  for (int s = 512; s > 0; s >>= 1) { if (tid < s) red[tid] += red[tid + s]; __syncthreads(); }
  if (tid == 0) { den[0] = m0; den[1] = Z0; den[2] = m1; den[3] = red[0]; }
}

__global__ __launch_bounds__(256) void fuse_emb(
    const float* __restrict__ e0, const float* __restrict__ e1,
    const float* __restrict__ s0, const float* __restrict__ s1,
    const float* __restrict__ den, float* __restrict__ out, int N)
{
  int idx = blockIdx.x * 256 + threadIdx.x;
  if (idx >= N * 128) return;
  int i = idx >> 7;
  float a0 = expf(s0[i] - den[0]) / den[1];
  float a1 = expf(s1[i] - den[2]) / den[3];
  out[idx] = fmaxf(a0 * e0[idx] + a1 * e1[idx], 0.f);
}

// ---------------------------------------------------------------------------
__global__ __launch_bounds__(256) void edge_d_kernel(
    const int* __restrict__ ud, const float* __restrict__ fe,
    const float* __restrict__ rel, float* __restrict__ partial, int En)
{
  int lane = threadIdx.x & 63;
  int wid = threadIdx.x >> 6;
  int gw = blockIdx.x * 4 + wid;
  int nw = gridDim.x * 4;
  float acc = 0.f;
  for (int e = gw; e < En; e += nw) {
    int4 ei = *reinterpret_cast<const int4*>(ud + (size_t)e * 4);
    const float* fi = fe + (size_t)ei.x * 128;
    const float* fj = fe + (size_t)ei.y * 128;
    const float* rr = rel + (size_t)ei.w * 128;
    float t0 = tanhf(fi[lane] + fj[lane]);
    float t1 = tanhf(fi[lane + 64] + fj[lane + 64]);
    float d = rr[lane] * t0 + rr[lane + 64] * t1;
#pragma unroll
    for (int o = 32; o > 0; o >>= 1) d += __shfl_down(d, o);
    if (lane == 0) {
      float x = (float)ei.z * d;
      acc += (x >= 0.f) ? log1pf(expf(-x)) : (-x + log1pf(expf(x)));
    }
  }
  __shared__ float red[4];
  if (lane == 0) red[wid] = acc;
  __syncthreads();
  if (threadIdx.x == 0) partial[blockIdx.x] = red[0] + red[1] + red[2] + red[3];
}

__global__ __launch_bounds__(256) void edge_s_kernel(
    const int* __restrict__ us, const float* __restrict__ fe,
    float* __restrict__ partial, int En)
{
  int lane = threadIdx.x & 63;
  int wid = threadIdx.x >> 6;
  int gw = blockIdx.x * 4 + wid;
  int nw = gridDim.x * 4;
  float acc = 0.f;
  for (int e = gw; e < En; e += nw) {
    int i = us[(size_t)e * 3], j = us[(size_t)e * 3 + 1], lab = us[(size_t)e * 3 + 2];
    const float* fi = fe + (size_t)i * 128;
    const float* fj = fe + (size_t)j * 128;
    float d = fi[lane] * fj[lane] + fi[lane + 64] * fj[lane + 64];
#pragma unroll
    for (int o = 32; o > 0; o >>= 1) d += __shfl_down(d, o);
    if (lane == 0) {
      float x = (float)lab * d;
      acc += (x >= 0.f) ? log1pf(expf(-x)) : (-x + log1pf(expf(x)));
    }
  }
  __shared__ float red[4];
  if (lane == 0) red[wid] = acc;
  __syncthreads();
  if (threadIdx.x == 0) partial[blockIdx.x] = red[0] + red[1] + red[2] + red[3];
}

__global__ void copy_kernel(const float* __restrict__ src, float* __restrict__ dst, int n) {
  int i = blockIdx.x * blockDim.x + threadIdx.x;
  if (i < n) dst[i] = src[i];
}

__global__ __launch_bounds__(1024) void finalize2(
    const float* __restrict__ pd, const float* __restrict__ ps,
    const float* __restrict__ parts, float* __restrict__ out)
{
  __shared__ float red[1024];
  int tid = threadIdx.x;
  red[tid] = pd[tid] + ps[tid];
  __syncthreads();
  for (int s = 512; s > 0; s >>= 1) { if (tid < s) red[tid] += red[tid + s]; __syncthreads(); }
  if (tid == 0)
    out[0] = red[0] + parts[0] + parts[1] + parts[2] + parts[3] + parts[4];
}

// ---------------------------------------------------------------------------
extern "C" void kernel_launch(void* const* d_in, const int* in_sizes, int n_in,
                              void* d_out, int out_size, void* d_ws, size_t ws_size,
                              hipStream_t stream)
{
  const float* feat_P = (const float*)d_in[0];
  const float* feat_V = (const float*)d_in[1];
  const float* feat_C = (const float*)d_in[2];
  const float* feat_A = (const float*)d_in[3];
  const float* W1 = (const float*)d_in[4];
  const float* b1 = (const float*)d_in[5];
  const float* W2 = (const float*)d_in[6];
  const float* b2 = (const float*)d_in[7];
  const float* W3 = (const float*)d_in[8];
  const float* b3 = (const float*)d_in[9];
  const float* L00W = (const float*)d_in[10];
  const float* L00b = (const float*)d_in[11];
  const float* L01W = (const float*)d_in[12];
  const float* L01b = (const float*)d_in[13];
  const float* L10W = (const float*)d_in[14];
  const float* L10b = (const float*)d_in[15];
  const float* L11W = (const float*)d_in[16];
  const float* L11b = (const float*)d_in[17];
  const float* L12W = (const float*)d_in[18];
  const float* L12b = (const float*)d_in[19];
  const float* g0_Wih = (const float*)d_in[20];
  const float* g0_Whh = (const float*)d_in[21];
  const float* g0_bih = (const float*)d_in[22];
  const float* g0_bhh = (const float*)d_in[23];
  const float* g1_Wih = (const float*)d_in[24];
  const float* g1_Whh = (const float*)d_in[25];
  const float* g1_bih = (const float*)d_in[26];
  const float* g1_bhh = (const float*)d_in[27];
  const float* rel_emb = (const float*)d_in[28];
  const float* adj00 = (const float*)d_in[29];
  const float* adj01 = (const float*)d_in[30];
  const float* adj10 = (const float*)d_in[31];
  const float* adj11 = (const float*)d_in[32];
  const float* adj12 = (const float*)d_in[33];
  const float* clsA = (const float*)d_in[34];
  const float* clsP = (const float*)d_in[35];
  const float* clsV = (const float*)d_in[36];
  const int* u_s = (const int*)d_in[37];
  const int* u_d = (const int*)d_in[38];

  float* out = (float*)d_out;
  float* fe = out + 1;                          // final_ent [18500,128]
  float* rel_out = out + 1 + 18500 * 128;       // rel_emb copy [12,128]

  float* ws = (float*)d_ws;
  size_t o = 0;
  auto alloc = [&](size_t n) { float* p = ws + o; o += n; return p; };
  float* selfb  = alloc(18500 * 128);           // self embeddings (P|V|C|A rows)
  float* gi     = alloc(8000 * 384);
  float* gh     = alloc(8000 * 384);
  float* logits = alloc((size_t)8000 * 1500);
  float* scaled = alloc(8000 * 128);
  float* hbuf   = alloc(8000 * 128);
  float* stP0 = alloc(8000 * 128);
  float* stA0 = alloc(6000 * 128);
  float* stP1 = alloc(8000 * 128);
  float* stV1 = alloc(3000 * 128);
  float* stC1 = alloc(1500 * 128);
  float* cebuf = alloc(5 * 8000);
  float* s0b = alloc(8000);
  float* s1b = alloc(8000);
  float* den = alloc(4);
  float* partial_d = alloc(1024);
  float* partial_s = alloc(1024);
  float* parts = alloc(8);
  // bf16 buffers (ushort), counted in float units (/2)
  auto allocb = [&](size_t nelem) { unsigned short* p = (unsigned short*)(ws + o); o += nelem / 2; return p; };
  unsigned short* featb = allocb((size_t)18500 * 128);  // P|V|C|A rows, matches fe layout
  unsigned short* stP0b = allocb(8000 * 128);
  unsigned short* stA0b = allocb(6000 * 128);
  unsigned short* stP1b = allocb(8000 * 128);
  unsigned short* stV1b = allocb(3000 * 128);
  unsigned short* stC1b = allocb(1500 * 128);
  unsigned short* hbufb = allocb(8000 * 128);
  unsigned short* W1b = allocb(128 * 128);
  unsigned short* L00Wb = allocb(1500 * 128);
  unsigned short* L01Wb = allocb(1500 * 128);
  unsigned short* L10Wb = allocb(1500 * 128);
  unsigned short* L11Wb = allocb(1500 * 128);
  unsigned short* L12Wb = allocb(1500 * 128);
  unsigned short* g0Wihb = allocb(384 * 128);
  unsigned short* g0Whhb = allocb(384 * 128);
  unsigned short* g1Wihb = allocb(384 * 128);
  unsigned short* g1Whhb = allocb(384 * 128);
  unsigned short* featPb = featb;
  unsigned short* featVb = featb + (size_t)8000 * 128;
  unsigned short* featCb = featb + (size_t)11000 * 128;
  unsigned short* featAb = featb + (size_t)12500 * 128;
  (void)ws_size; (void)in_sizes; (void)n_in; (void)out_size;

  dim3 blk(256);

  // --- one batched f32->bf16 conversion ---
  CvtArgs ca{};
  int nseg = 0, totblk = 0;
  auto addseg = [&](const float* src, unsigned short* dst, int n) {
    ca.seg[nseg].src = src; ca.seg[nseg].dst = dst; ca.seg[nseg].n = n;
    ca.seg[nseg].nblk = (n + 1023) / 1024; totblk += ca.seg[nseg].nblk; ++nseg;
  };
  addseg(feat_P, featPb, 8000 * 128);
  addseg(feat_V, featVb, 3000 * 128);
  addseg(feat_C, featCb, 1500 * 128);
  addseg(feat_A, featAb, 6000 * 128);
  addseg(W1, W1b, 128 * 128);
  addseg(L00W, L00Wb, 1500 * 128);
  addseg(L01W, L01Wb, 1500 * 128);
  addseg(L10W, L10Wb, 1500 * 128);
  addseg(L11W, L11Wb, 1500 * 128);
  addseg(L12W, L12Wb, 1500 * 128);
  addseg(g0_Wih, g0Wihb, 384 * 128);
  addseg(g0_Whh, g0Whhb, 384 * 128);
  addseg(g1_Wih, g1Wihb, 384 * 128);
  addseg(g1_Whh, g1Whhb, 384 * 128);
  ca.nseg = nseg;
  hipLaunchKernelGGL(convert_bf16_many, dim3(totblk), blk, 0, stream, ca);

  auto gemm = [&](const unsigned short* Xb, const unsigned short* Wb,
                  const float* b, float* C, int N, int O) {
    dim3 g((N + 127) / 128, (O + 63) / 64);
    hipLaunchKernelGGL(gemm_bf16, g, blk, 0, stream, Xb, Wb, b, C, N, O);
  };

  // self embeddings: one batched GEMM over all 18500 rows
  gemm(featb, W1b, b1, selfb, 18500, 128);
  float* selfP = selfb;
  float* selfV = selfb + (size_t)8000 * 128;
  float* selfC = selfb + (size_t)11000 * 128;
  float* selfA = selfb + (size_t)12500 * 128;

  auto run_stage = [&](int sidx, const unsigned short* xlogb, const float* xlog, int Nl,
                       const unsigned short* LWb, const float* Lb, const float* cls,
                       const float* adj, int M,
                       const unsigned short* xfeatb,
                       const unsigned short* Wihb, const float* bih,
                       const unsigned short* Whhb, const float* bhh,
                       float* state, unsigned short* stateb) {
    gemm(xlogb, LWb, Lb, logits, Nl, 1500);
    hipLaunchKernelGGL(rowops_kernel, dim3(Nl), blk, 0, stream, logits, cls, xlog, scaled,
                       cebuf + sidx * 8000, Nl);
    hipLaunchKernelGGL(spmv_scan, dim3(M), blk, 0, stream, adj, scaled, hbuf, hbufb, M, Nl);
    gemm(xfeatb, Wihb, bih, gi, M, 384);
    gemm(hbufb, Whhb, bhh, gh, M, 384);
    hipLaunchKernelGGL(gru_elem, dim3((M * 32 + 255) / 256), blk, 0, stream, gi, gh, hbuf,
                       state, stateb, M);
  };

  run_stage(0, featVb, feat_V, 3000, L00Wb, L00b, clsV, adj00, 8000,
            featPb, g0Wihb, g0_bih, g0Whhb, g0_bhh, stP0, stP0b);
  run_stage(1, stP0b, stP0, 8000, L01Wb, L01b, clsP, adj01, 6000,
            featAb, g0Wihb, g0_bih, g0Whhb, g0_bhh, stA0, stA0b);
  run_stage(2, featAb, feat_A, 6000, L10Wb, L10b, clsA, adj10, 8000,
            featPb, g1Wihb, g1_bih, g1Whhb, g1_bhh, stP1, stP1b);
  run_stage(3, stP1b, stP1, 8000, L11Wb, L11b, clsP, adj11, 3000,
            featVb, g1Wihb, g1_bih, g1Whhb, g1_bhh, stV1, stV1b);
  run_stage(4, stV1b, stV1, 3000, L12Wb, L12b, clsV, adj12, 1500,
            featCb, g1Wihb, g1_bih, g1Whhb, g1_bhh, stC1, stC1b);

  hipLaunchKernelGGL(ce_reduce5, dim3(5), blk, 0, stream, cebuf, parts);

  auto fuse = [&](const float* e0, const float* e1, int N, int off) {
    hipLaunchKernelGGL(fuse_scores, dim3((N + 3) / 4), blk, 0, stream, e0, e1, W2, b2, W3, b3, s0b, s1b, N);
    hipLaunchKernelGGL(softmax_denom, dim3(1), dim3(1024), 0, stream, s0b, s1b, den, N);
    hipLaunchKernelGGL(fuse_emb, dim3((N * 128 + 255) / 256), blk, 0, stream, e0, e1, s0b, s1b, den,
                       fe + (size_t)off * 128, N);
  };
  fuse(selfP, stP0, 8000, 0);
  fuse(selfV, stV1, 3000, 8000);
  fuse(selfC, stC1, 1500, 11000);
  fuse(selfA, stA0, 6000, 12500);

  hipLaunchKernelGGL(copy_kernel, dim3(6), blk, 0, stream, rel_emb, rel_out, 12 * 128);

  hipLaunchKernelGGL(edge_d_kernel, dim3(1024), blk, 0, stream, u_d, fe, rel_emb, partial_d, 150000);
  hipLaunchKernelGGL(edge_s_kernel, dim3(1024), blk, 0, stream, u_s, fe, partial_s, 150000);

  hipLaunchKernelGGL(finalize2, dim3(1), dim3(1024), 0, stream, partial_d, partial_s, parts, out);
}

// Round 4
// 627.320 us; speedup vs baseline: 39.6310x; 1.1902x over previous
//
#include <hip/hip_runtime.h>
#include <cstdint>
#include <cstddef>

#define DEV_INLINE __device__ __forceinline__

typedef __attribute__((ext_vector_type(8))) short bf16x8;
typedef __attribute__((ext_vector_type(16))) float f32x16;
struct __align__(8) US4 { unsigned short u[4]; };

DEV_INLINE unsigned short f2bf(float x) {
  unsigned u = __float_as_uint(x);
  return (unsigned short)((u + 0x7FFFu + ((u >> 16) & 1u)) >> 16);
}

// ---------------------------------------------------------------------------
// Batched f32 -> bf16 conversion (one launch for feats + all weights)
// ---------------------------------------------------------------------------
struct CvtSeg { const float* src; unsigned short* dst; int n; int nblk; };
struct CvtArgs { CvtSeg seg[16]; int nseg; };

__global__ __launch_bounds__(256) void convert_bf16_many(CvtArgs args) {
  int b = blockIdx.x;
  int s = 0;
  while (s < args.nseg && b >= args.seg[s].nblk) { b -= args.seg[s].nblk; ++s; }
  if (s >= args.nseg) return;
  int base = b * 1024 + threadIdx.x * 4;
  if (base >= args.seg[s].n) return;
  float4 v = *reinterpret_cast<const float4*>(args.seg[s].src + base);
  US4 o;
  o.u[0] = f2bf(v.x); o.u[1] = f2bf(v.y); o.u[2] = f2bf(v.z); o.u[3] = f2bf(v.w);
  *reinterpret_cast<US4*>(args.seg[s].dst + base) = o;
}

// ---------------------------------------------------------------------------
// bf16 MFMA GEMM body: C[N,O] = Xb[N,128] @ Wb[O,128]^T + bias[O] (f32 out)
// Block 256 thr = 4 waves; tile 128(M)x64(N); mfma_f32_32x32x16_bf16 x8 Ksteps.
// LDS bf16 tiles XOR-swizzled (c16 ^ (row&7)).
// ---------------------------------------------------------------------------
DEV_INLINE void gemm_body(
    const unsigned short* __restrict__ Xb, const unsigned short* __restrict__ Wb,
    const float* __restrict__ bias, float* __restrict__ C, int N, int O,
    int bm, int bn, unsigned short* Xs, unsigned short* Ws)
{
  const int tid = threadIdx.x;
#pragma unroll
  for (int i = 0; i < 8; ++i) {
    int s = tid + 256 * i;           // 0..2047
    int row = s >> 4, c16 = s & 15;
    uint4 v = make_uint4(0, 0, 0, 0);
    int gr = bm + row;
    if (gr < N) v = *reinterpret_cast<const uint4*>(Xb + (size_t)gr * 128 + c16 * 8);
    *reinterpret_cast<uint4*>(&Xs[(row * 16 + (c16 ^ (row & 7))) * 8]) = v;
  }
#pragma unroll
  for (int i = 0; i < 4; ++i) {
    int s = tid + 256 * i;           // 0..1023
    int row = s >> 4, c16 = s & 15;
    uint4 v = make_uint4(0, 0, 0, 0);
    int gw = bn + row;
    if (gw < O) v = *reinterpret_cast<const uint4*>(Wb + (size_t)gw * 128 + c16 * 8);
    *reinterpret_cast<uint4*>(&Ws[(row * 16 + (c16 ^ (row & 7))) * 8]) = v;
  }
  __syncthreads();

  const int wave = tid >> 6, lane = tid & 63;
  const int l31 = lane & 31, lhi = lane >> 5;

  f32x16 acc0, acc1;
#pragma unroll
  for (int i = 0; i < 16; ++i) { acc0[i] = 0.f; acc1[i] = 0.f; }

  const int ar = wave * 32 + l31;
#pragma unroll
  for (int ks = 0; ks < 8; ++ks) {
    int c16 = ks * 2 + lhi;
    bf16x8 a  = *reinterpret_cast<const bf16x8*>(&Xs[(ar * 16 + (c16 ^ (ar & 7))) * 8]);
    bf16x8 b0 = *reinterpret_cast<const bf16x8*>(&Ws[(l31 * 16 + (c16 ^ (l31 & 7))) * 8]);
    int br1 = 32 + l31;
    bf16x8 b1 = *reinterpret_cast<const bf16x8*>(&Ws[(br1 * 16 + (c16 ^ (br1 & 7))) * 8]);
    acc0 = __builtin_amdgcn_mfma_f32_32x32x16_bf16(a, b0, acc0, 0, 0, 0);
    acc1 = __builtin_amdgcn_mfma_f32_32x32x16_bf16(a, b1, acc1, 0, 0, 0);
  }

  // C/D layout: col = lane&31, row = (reg&3) + 8*(reg>>2) + 4*(lane>>5)
#pragma unroll
  for (int reg = 0; reg < 16; ++reg) {
    int r = bm + wave * 32 + (reg & 3) + 8 * (reg >> 2) + 4 * lhi;
    if (r < N) {
      int c0 = bn + l31;
      if (c0 < O) C[(size_t)r * O + c0] = acc0[reg] + bias[c0];
      int c1 = bn + 32 + l31;
      if (c1 < O) C[(size_t)r * O + c1] = acc1[reg] + bias[c1];
    }
  }
}

__global__ __launch_bounds__(256) void gemm_bf16(
    const unsigned short* __restrict__ Xb, const unsigned short* __restrict__ Wb,
    const float* __restrict__ bias, float* __restrict__ C, int N, int O)
{
  __shared__ __align__(16) unsigned short Xs[128 * 128];
  __shared__ __align__(16) unsigned short Ws[64 * 128];
  gemm_body(Xb, Wb, bias, C, N, O, blockIdx.x * 128, blockIdx.y * 64, Xs, Ws);
}

// Batched segment GEMM (all gi GEMMs in one launch; shared O)
struct GemmSeg { const unsigned short* X; const unsigned short* W; const float* bias; float* C; int N; int blk0; };
struct GemmSegs { GemmSeg s[5]; int nseg; };

__global__ __launch_bounds__(256) void gemm_bf16_seg(GemmSegs segs, int O) {
  __shared__ __align__(16) unsigned short Xs[128 * 128];
  __shared__ __align__(16) unsigned short Ws[64 * 128];
  int bx = blockIdx.x;
  int si = 0;
  while (si + 1 < segs.nseg && bx >= segs.s[si + 1].blk0) ++si;
  const GemmSeg& sg = segs.s[si];
  gemm_body(sg.X, sg.W, sg.bias, sg.C, sg.N, O,
            (bx - sg.blk0) * 128, blockIdx.y * 64, Xs, Ws);
}

// ---------------------------------------------------------------------------
// Sparse row scan: H[M,128] = A[M,K] @ Xs[K,128]; also emits bf16 copy of H.
// ---------------------------------------------------------------------------
__global__ __launch_bounds__(256) void spmv_scan(
    const float* __restrict__ A, const float* __restrict__ Xs,
    float* __restrict__ H, unsigned short* __restrict__ Hb, int M, int K)
{
  int row = blockIdx.x;
  int tid = threadIdx.x, wave = tid >> 6, lane = tid & 63;
  const float4* Arow = reinterpret_cast<const float4*>(A + (size_t)row * K);
  int K4 = K >> 2;
  float acc0 = 0.f, acc1 = 0.f;
  for (int base = wave * 64; base < K4; base += 256) {
    int q = base + lane;
    float4 a = (q < K4) ? Arow[q] : make_float4(0.f, 0.f, 0.f, 0.f);
#pragma unroll
    for (int c = 0; c < 4; ++c) {
      float av = (c == 0) ? a.x : (c == 1) ? a.y : (c == 2) ? a.z : a.w;
      unsigned long long mm = __ballot(av != 0.f);
      while (mm) {
        int b = __builtin_ctzll(mm);
        mm &= mm - 1;
        float v = __shfl(av, b);
        int jj = (base + b) * 4 + c;
        const float* xr = Xs + (size_t)jj * 128;
        acc0 += v * xr[lane];
        acc1 += v * xr[lane + 64];
      }
    }
  }
  __shared__ float red[4][128];
  red[wave][lane] = acc0;
  red[wave][lane + 64] = acc1;
  __syncthreads();
  if (wave == 0) {
    float r0 = red[0][lane] + red[1][lane] + red[2][lane] + red[3][lane];
    float r1 = red[0][lane + 64] + red[1][lane + 64] + red[2][lane + 64] + red[3][lane + 64];
    H[(size_t)row * 128 + lane] = r0;
    H[(size_t)row * 128 + 64 + lane] = r1;
    Hb[(size_t)row * 128 + lane] = f2bf(r0);
    Hb[(size_t)row * 128 + 64 + lane] = f2bf(r1);
  }
}

// ---------------------------------------------------------------------------
DEV_INLINE float br_max(float v, float* red) {
  int tid = threadIdx.x;
  red[tid] = v; __syncthreads();
#pragma unroll
  for (int s = 128; s > 0; s >>= 1) { if (tid < s) red[tid] = fmaxf(red[tid], red[tid + s]); __syncthreads(); }
  float r = red[0]; __syncthreads();
  return r;
}
DEV_INLINE float br_sum(float v, float* red) {
  int tid = threadIdx.x;
  red[tid] = v; __syncthreads();
#pragma unroll
  for (int s = 128; s > 0; s >>= 1) { if (tid < s) red[tid] += red[tid + s]; __syncthreads(); }
  float r = red[0]; __syncthreads();
  return r;
}

// ---------------------------------------------------------------------------
// Per-row softmax / CE (softmax-of-softmax, max(p)=1/Z1) / tcp scaling.
// ---------------------------------------------------------------------------
__global__ __launch_bounds__(256) void rowops_kernel(
    const float* __restrict__ logits, const float* __restrict__ cls,
    const float* __restrict__ src, float* __restrict__ scaled,
    float* __restrict__ ce, int N)
{
  __shared__ float ls[1500];
  __shared__ float red[256];
  __shared__ float tbc;
  int row = blockIdx.x;
  int tid = threadIdx.x;
  const float4* lr4 = reinterpret_cast<const float4*>(logits + (size_t)row * 1500);
  float m = -3.4e38f;
  for (int j = tid; j < 375; j += 256) {
    float4 v = lr4[j];
    *reinterpret_cast<float4*>(&ls[j * 4]) = v;
    m = fmaxf(fmaxf(m, fmaxf(v.x, v.y)), fmaxf(v.z, v.w));
  }
  float m1 = br_max(m, red);
  float z = 0.f;
  for (int j = tid; j < 375; j += 256) {
    float4 v = *reinterpret_cast<float4*>(&ls[j * 4]);
    v.x = expf(v.x - m1); v.y = expf(v.y - m1);
    v.z = expf(v.z - m1); v.w = expf(v.w - m1);
    *reinterpret_cast<float4*>(&ls[j * 4]) = v;
    z += (v.x + v.y) + (v.z + v.w);
  }
  float Z1 = br_sum(z, red);
  float invZ1 = 1.0f / Z1;
  float m2 = invZ1;  // max(p) == 1/Z1 exactly
  const float4* cr4 = reinterpret_cast<const float4*>(cls + (size_t)row * 1500);
  float t = 0.f, lsum = 0.f, z2 = 0.f;
  for (int j = tid; j < 375; j += 256) {
    float4 p = *reinterpret_cast<float4*>(&ls[j * 4]);
    float4 c = cr4[j];
    p.x *= invZ1; p.y *= invZ1; p.z *= invZ1; p.w *= invZ1;
    t += c.x * p.x + c.y * p.y + c.z * p.z + c.w * p.w;
    lsum += (c.x + c.y) + (c.z + c.w);
    z2 += expf(p.x - m2) + expf(p.y - m2) + expf(p.z - m2) + expf(p.w - m2);
  }
  t = br_sum(t, red);
  lsum = br_sum(lsum, red);
  z2 = br_sum(z2, red);
  if (tid == 0) { ce[row] = t - lsum * (m2 + logf(z2)); tbc = t; }
  __syncthreads();
  if (tid < 128) scaled[(size_t)row * 128 + tid] = tbc * src[(size_t)row * 128 + tid];
}

// ---------------------------------------------------------------------------
// GRU elementwise, 4 elems/thread; emits f32 state + bf16 copy.
// ---------------------------------------------------------------------------
__global__ __launch_bounds__(256) void gru_elem(
    const float* __restrict__ gi, const float* __restrict__ gh,
    const float* __restrict__ h, float* __restrict__ out,
    unsigned short* __restrict__ outb, int N)
{
  int q = blockIdx.x * 256 + threadIdx.x;
  if (q >= N * 32) return;
  int i = q >> 5, d4 = (q & 31) * 4;
  const float* gir = gi + (size_t)i * 384;
  const float* ghr = gh + (size_t)i * 384;
  float4 ir4 = *reinterpret_cast<const float4*>(gir + d4);
  float4 iz4 = *reinterpret_cast<const float4*>(gir + 128 + d4);
  float4 in4 = *reinterpret_cast<const float4*>(gir + 256 + d4);
  float4 hr4 = *reinterpret_cast<const float4*>(ghr + d4);
  float4 hz4 = *reinterpret_cast<const float4*>(ghr + 128 + d4);
  float4 hn4 = *reinterpret_cast<const float4*>(ghr + 256 + d4);
  float4 hv4 = *reinterpret_cast<const float4*>(h + (size_t)i * 128 + d4);
  float4 o4;
  {
    float r = 1.f / (1.f + expf(-(ir4.x + hr4.x)));
    float zz = 1.f / (1.f + expf(-(iz4.x + hz4.x)));
    float n = tanhf(in4.x + r * hn4.x);
    o4.x = (1.f - zz) * n + zz * hv4.x;
  }
  {
    float r = 1.f / (1.f + expf(-(ir4.y + hr4.y)));
    float zz = 1.f / (1.f + expf(-(iz4.y + hz4.y)));
    float n = tanhf(in4.y + r * hn4.y);
    o4.y = (1.f - zz) * n + zz * hv4.y;
  }
  {
    float r = 1.f / (1.f + expf(-(ir4.z + hr4.z)));
    float zz = 1.f / (1.f + expf(-(iz4.z + hz4.z)));
    float n = tanhf(in4.z + r * hn4.z);
    o4.z = (1.f - zz) * n + zz * hv4.z;
  }
  {
    float r = 1.f / (1.f + expf(-(ir4.w + hr4.w)));
    float zz = 1.f / (1.f + expf(-(iz4.w + hz4.w)));
    float n = tanhf(in4.w + r * hn4.w);
    o4.w = (1.f - zz) * n + zz * hv4.w;
  }
  *reinterpret_cast<float4*>(out + (size_t)i * 128 + d4) = o4;
  US4 ob;
  ob.u[0] = f2bf(o4.x); ob.u[1] = f2bf(o4.y); ob.u[2] = f2bf(o4.z); ob.u[3] = f2bf(o4.w);
  *reinterpret_cast<US4*>(outb + (size_t)i * 128 + d4) = ob;
}

// ---------------------------------------------------------------------------
// Fuse pipeline, flattened over all 18500 entity rows.
// e0 = selfb (P|V|C|A), e1 = stcat (P0|V1|C1|A0), same row layout as fe.
// ---------------------------------------------------------------------------
__global__ __launch_bounds__(256) void fuse_scores_all(
    const float* __restrict__ e0, const float* __restrict__ e1,
    const float* __restrict__ W2, const float* __restrict__ b2,
    const float* __restrict__ W3, const float* __restrict__ b3,
    float* __restrict__ s0, float* __restrict__ s1)
{
  int lane = threadIdx.x & 63;
  int row = (blockIdx.x * 256 + threadIdx.x) >> 6;
  if (row >= 18500) return;
  float a0 = e0[(size_t)row * 128 + lane] * W2[lane] + e0[(size_t)row * 128 + 64 + lane] * W2[64 + lane];
  float a1 = e1[(size_t)row * 128 + lane] * W3[lane] + e1[(size_t)row * 128 + 64 + lane] * W3[64 + lane];
#pragma unroll
  for (int o = 32; o > 0; o >>= 1) { a0 += __shfl_down(a0, o); a1 += __shfl_down(a1, o); }
  if (lane == 0) {
    s0[row] = fmaxf(a0 + b2[0], 0.f);
    s1[row] = fmaxf(a1 + b3[0], 0.f);
  }
}

// 4 blocks, one per entity: den[b*4..] = {m0, Z0, m1, Z1}
__global__ __launch_bounds__(1024) void denom4(
    const float* __restrict__ s0, const float* __restrict__ s1,
    float* __restrict__ den)
{
  __shared__ float red[1024];
  const int ns[4]   = {8000, 3000, 1500, 6000};
  const int offs[4] = {0, 8000, 11000, 12500};
  int b = blockIdx.x;
  int n = ns[b];
  const float* p0 = s0 + offs[b];
  const float* p1 = s1 + offs[b];
  int tid = threadIdx.x;
  float m = -3.4e38f;
  for (int i = tid; i < n; i += 1024) m = fmaxf(m, p0[i]);
  red[tid] = m; __syncthreads();
  for (int s = 512; s > 0; s >>= 1) { if (tid < s) red[tid] = fmaxf(red[tid], red[tid + s]); __syncthreads(); }
  float m0 = red[0]; __syncthreads();
  float z = 0.f;
  for (int i = tid; i < n; i += 1024) z += expf(p0[i] - m0);
  red[tid] = z; __syncthreads();
  for (int s = 512; s > 0; s >>= 1) { if (tid < s) red[tid] += red[tid + s]; __syncthreads(); }
  float Z0 = red[0]; __syncthreads();
  m = -3.4e38f;
  for (int i = tid; i < n; i += 1024) m = fmaxf(m, p1[i]);
  red[tid] = m; __syncthreads();
  for (int s = 512; s > 0; s >>= 1) { if (tid < s) red[tid] = fmaxf(red[tid], red[tid + s]); __syncthreads(); }
  float m1 = red[0]; __syncthreads();
  z = 0.f;
  for (int i = tid; i < n; i += 1024) z += expf(p1[i] - m1);
  red[tid] = z; __syncthreads();
  for (int s = 512; s > 0; s >>= 1) { if (tid < s) red[tid] += red[tid + s]; __syncthreads(); }
  if (tid == 0) { den[b * 4] = m0; den[b * 4 + 1] = Z0; den[b * 4 + 2] = m1; den[b * 4 + 3] = red[0]; }
}

// flat over 18500*128 (+1536 rel copy appended)
__global__ __launch_bounds__(256) void fuse_emb_all(
    const float* __restrict__ e0, const float* __restrict__ e1,
    const float* __restrict__ s0, const float* __restrict__ s1,
    const float* __restrict__ den, const float* __restrict__ rel,
    float* __restrict__ fe, float* __restrict__ rel_out)
{
  int idx = blockIdx.x * 256 + threadIdx.x;
  const int tot = 18500 * 128;
  if (idx < tot) {
    int row = idx >> 7;
    int e = (row < 8000) ? 0 : (row < 11000) ? 1 : (row < 12500) ? 2 : 3;
    float a0 = expf(s0[row] - den[e * 4]) / den[e * 4 + 1];
    float a1 = expf(s1[row] - den[e * 4 + 2]) / den[e * 4 + 3];
    fe[idx] = fmaxf(a0 * e0[idx] + a1 * e1[idx], 0.f);
  } else if (idx < tot + 1536) {
    rel_out[idx - tot] = rel[idx - tot];
  }
}

// ---------------------------------------------------------------------------
// Edge losses, both sets in one launch: blocks [0,1024) -> u_d, [1024,2048) -> u_s
// ---------------------------------------------------------------------------
__global__ __launch_bounds__(256) void edge_both(
    const int* __restrict__ ud, const int* __restrict__ us,
    const float* __restrict__ fe, const float* __restrict__ rel,
    float* __restrict__ partial, int En)
{
  int lane = threadIdx.x & 63;
  int wid = threadIdx.x >> 6;
  bool is_d = (blockIdx.x < 1024);
  int bb = is_d ? blockIdx.x : blockIdx.x - 1024;
  int gw = bb * 4 + wid;
  const int nw = 1024 * 4;
  float acc = 0.f;
  if (is_d) {
    for (int e = gw; e < En; e += nw) {
      int4 ei = *reinterpret_cast<const int4*>(ud + (size_t)e * 4);
      const float* fi = fe + (size_t)ei.x * 128;
      const float* fj = fe + (size_t)ei.y * 128;
      const float* rr = rel + (size_t)ei.w * 128;
      float t0 = tanhf(fi[lane] + fj[lane]);
      float t1 = tanhf(fi[lane + 64] + fj[lane + 64]);
      float d = rr[lane] * t0 + rr[lane + 64] * t1;
#pragma unroll
      for (int o = 32; o > 0; o >>= 1) d += __shfl_down(d, o);
      if (lane == 0) {
        float x = (float)ei.z * d;
        acc += (x >= 0.f) ? log1pf(expf(-x)) : (-x + log1pf(expf(x)));
      }
    }
  } else {
    for (int e = gw; e < En; e += nw) {
      int i = us[(size_t)e * 3], j = us[(size_t)e * 3 + 1], lab = us[(size_t)e * 3 + 2];
      const float* fi = fe + (size_t)i * 128;
      const float* fj = fe + (size_t)j * 128;
      float d = fi[lane] * fj[lane] + fi[lane + 64] * fj[lane + 64];
#pragma unroll
      for (int o = 32; o > 0; o >>= 1) d += __shfl_down(d, o);
      if (lane == 0) {
        float x = (float)lab * d;
        acc += (x >= 0.f) ? log1pf(expf(-x)) : (-x + log1pf(expf(x)));
      }
    }
  }
  __shared__ float red[4];
  if (lane == 0) red[wid] = acc;
  __syncthreads();
  if (threadIdx.x == 0) partial[blockIdx.x] = red[0] + red[1] + red[2] + red[3];
}

// ---------------------------------------------------------------------------
// Final: loss = sum(partial[0..2047]) + sum_s -mean(ce_seg_s)
// ---------------------------------------------------------------------------
__global__ __launch_bounds__(1024) void final_reduce(
    const float* __restrict__ partial, const float* __restrict__ cebuf,
    float* __restrict__ out)
{
  __shared__ float red[1024];
  __shared__ float total;
  int tid = threadIdx.x;
  if (tid == 0) total = 0.f;
  __syncthreads();
  float a = partial[tid] + partial[tid + 1024];
  red[tid] = a; __syncthreads();
  for (int s = 512; s > 0; s >>= 1) { if (tid < s) red[tid] += red[tid + s]; __syncthreads(); }
  if (tid == 0) total += red[0];
  __syncthreads();
  const int ns[5] = {3000, 8000, 6000, 8000, 3000};
#pragma unroll
  for (int seg = 0; seg < 5; ++seg) {
    const float* v = cebuf + seg * 8000;
    float s = 0.f;
    for (int i = tid; i < ns[seg]; i += 1024) s += v[i];
    red[tid] = s; __syncthreads();
    for (int st = 512; st > 0; st >>= 1) { if (tid < st) red[tid] += red[tid + st]; __syncthreads(); }
    if (tid == 0) total -= red[0] / (float)ns[seg];
    __syncthreads();
  }
  if (tid == 0) out[0] = total;
}

// ---------------------------------------------------------------------------
extern "C" void kernel_launch(void* const* d_in, const int* in_sizes, int n_in,
                              void* d_out, int out_size, void* d_ws, size_t ws_size,
                              hipStream_t stream)
{
  const float* feat_P = (const float*)d_in[0];
  const float* feat_V = (const float*)d_in[1];
  const float* feat_C = (const float*)d_in[2];
  const float* feat_A = (const float*)d_in[3];
  const float* W1 = (const float*)d_in[4];
  const float* b1 = (const float*)d_in[5];
  const float* W2 = (const float*)d_in[6];
  const float* b2 = (const float*)d_in[7];
  const float* W3 = (const float*)d_in[8];
  const float* b3 = (const float*)d_in[9];
  const float* L00W = (const float*)d_in[10];
  const float* L00b = (const float*)d_in[11];
  const float* L01W = (const float*)d_in[12];
  const float* L01b = (const float*)d_in[13];
  const float* L10W = (const float*)d_in[14];
  const float* L10b = (const float*)d_in[15];
  const float* L11W = (const float*)d_in[16];
  const float* L11b = (const float*)d_in[17];
  const float* L12W = (const float*)d_in[18];
  const float* L12b = (const float*)d_in[19];
  const float* g0_Wih = (const float*)d_in[20];
  const float* g0_Whh = (const float*)d_in[21];
  const float* g0_bih = (const float*)d_in[22];
  const float* g0_bhh = (const float*)d_in[23];
  const float* g1_Wih = (const float*)d_in[24];
  const float* g1_Whh = (const float*)d_in[25];
  const float* g1_bih = (const float*)d_in[26];
  const float* g1_bhh = (const float*)d_in[27];
  const float* rel_emb = (const float*)d_in[28];
  const float* adj00 = (const float*)d_in[29];
  const float* adj01 = (const float*)d_in[30];
  const float* adj10 = (const float*)d_in[31];
  const float* adj11 = (const float*)d_in[32];
  const float* adj12 = (const float*)d_in[33];
  const float* clsA = (const float*)d_in[34];
  const float* clsP = (const float*)d_in[35];
  const float* clsV = (const float*)d_in[36];
  const int* u_s = (const int*)d_in[37];
  const int* u_d = (const int*)d_in[38];

  float* out = (float*)d_out;
  float* fe = out + 1;                          // final_ent [18500,128]
  float* rel_out = out + 1 + 18500 * 128;       // rel_emb copy [12,128]

  float* ws = (float*)d_ws;
  size_t o = 0;
  auto alloc = [&](size_t n) { float* p = ws + o; o += n; return p; };
  float* selfb  = alloc((size_t)18500 * 128);   // self embeddings (P|V|C|A rows)
  float* stcat  = alloc((size_t)18500 * 128);   // states fused: P0|V1|C1|A0
  float* stP1   = alloc((size_t)8000 * 128);    // P1 (only feeds stage-3 logits)
  float* gi     = alloc((size_t)26500 * 384);   // all 5 stages concatenated
  float* gh     = alloc((size_t)8000 * 384);
  float* logits = alloc((size_t)8000 * 1500);
  float* scaled = alloc((size_t)8000 * 128);
  float* hbuf   = alloc((size_t)8000 * 128);
  float* cebuf  = alloc(5 * 8000);
  float* s0b = alloc(18500);
  float* s1b = alloc(18500);
  float* den = alloc(16);
  float* partial = alloc(2048);
  // bf16 buffers (ushort), counted in float units (/2)
  auto allocb = [&](size_t nelem) { unsigned short* p = (unsigned short*)(ws + o); o += nelem / 2; return p; };
  unsigned short* featb  = allocb((size_t)18500 * 128);  // P|V|C|A rows
  unsigned short* stcatb = allocb((size_t)18500 * 128);  // bf16 mirror of stcat
  unsigned short* stP1b  = allocb((size_t)8000 * 128);
  unsigned short* hbufb  = allocb((size_t)8000 * 128);
  unsigned short* W1b = allocb(128 * 128);
  unsigned short* L00Wb = allocb(1500 * 128);
  unsigned short* L01Wb = allocb(1500 * 128);
  unsigned short* L10Wb = allocb(1500 * 128);
  unsigned short* L11Wb = allocb(1500 * 128);
  unsigned short* L12Wb = allocb(1500 * 128);
  unsigned short* g0Wihb = allocb(384 * 128);
  unsigned short* g0Whhb = allocb(384 * 128);
  unsigned short* g1Wihb = allocb(384 * 128);
  unsigned short* g1Whhb = allocb(384 * 128);
  unsigned short* featPb = featb;
  unsigned short* featVb = featb + (size_t)8000 * 128;
  unsigned short* featCb = featb + (size_t)11000 * 128;
  unsigned short* featAb = featb + (size_t)12500 * 128;
  // state slices (stcat layout P0|V1|C1|A0 matches selfb/fe row order)
  float* stP0 = stcat;
  float* stV1 = stcat + (size_t)8000 * 128;
  float* stC1 = stcat + (size_t)11000 * 128;
  float* stA0 = stcat + (size_t)12500 * 128;
  unsigned short* stP0b = stcatb;
  unsigned short* stV1b = stcatb + (size_t)8000 * 128;
  unsigned short* stC1b = stcatb + (size_t)11000 * 128;
  unsigned short* stA0b = stcatb + (size_t)12500 * 128;
  (void)ws_size; (void)in_sizes; (void)n_in; (void)out_size;

  dim3 blk(256);

  // --- one batched f32->bf16 conversion ---
  CvtArgs ca{};
  int nseg = 0, totblk = 0;
  auto addseg = [&](const float* src, unsigned short* dst, int n) {
    ca.seg[nseg].src = src; ca.seg[nseg].dst = dst; ca.seg[nseg].n = n;
    ca.seg[nseg].nblk = (n + 1023) / 1024; totblk += ca.seg[nseg].nblk; ++nseg;
  };
  addseg(feat_P, featPb, 8000 * 128);
  addseg(feat_V, featVb, 3000 * 128);
  addseg(feat_C, featCb, 1500 * 128);
  addseg(feat_A, featAb, 6000 * 128);
  addseg(W1, W1b, 128 * 128);
  addseg(L00W, L00Wb, 1500 * 128);
  addseg(L01W, L01Wb, 1500 * 128);
  addseg(L10W, L10Wb, 1500 * 128);
  addseg(L11W, L11Wb, 1500 * 128);
  addseg(L12W, L12Wb, 1500 * 128);
  addseg(g0_Wih, g0Wihb, 384 * 128);
  addseg(g0_Whh, g0Whhb, 384 * 128);
  addseg(g1_Wih, g1Wihb, 384 * 128);
  addseg(g1_Whh, g1Whhb, 384 * 128);
  ca.nseg = nseg;
  hipLaunchKernelGGL(convert_bf16_many, dim3(totblk), blk, 0, stream, ca);

  auto gemm = [&](const unsigned short* Xb, const unsigned short* Wb,
                  const float* b, float* C, int N, int O) {
    dim3 g((N + 127) / 128, (O + 63) / 64);
    hipLaunchKernelGGL(gemm_bf16, g, blk, 0, stream, Xb, Wb, b, C, N, O);
  };

  // self embeddings: one batched GEMM over all 18500 rows
  gemm(featb, W1b, b1, selfb, 18500, 128);

  // all 5 gi GEMMs (independent of the chain) in ONE launch
  const int giM[5] = {8000, 6000, 8000, 3000, 1500};
  const size_t giOff[5] = {0, 8000, 14000, 22000, 25000};
  {
    GemmSegs gs{};
    const unsigned short* gx[5] = {featPb, featAb, featPb, featVb, featCb};
    const unsigned short* gw[5] = {g0Wihb, g0Wihb, g1Wihb, g1Wihb, g1Wihb};
    const float* gbias[5] = {g0_bih, g0_bih, g1_bih, g1_bih, g1_bih};
    int blk0 = 0;
    for (int s = 0; s < 5; ++s) {
      gs.s[s].X = gx[s]; gs.s[s].W = gw[s]; gs.s[s].bias = gbias[s];
      gs.s[s].C = gi + giOff[s] * 384; gs.s[s].N = giM[s]; gs.s[s].blk0 = blk0;
      blk0 += (giM[s] + 127) / 128;
    }
    gs.nseg = 5;
    hipLaunchKernelGGL(gemm_bf16_seg, dim3(blk0, 6), blk, 0, stream, gs, 384);
  }

  auto run_stage = [&](int sidx, const unsigned short* xlogb, const float* xlog, int Nl,
                       const unsigned short* LWb, const float* Lb, const float* cls,
                       const float* adj, int M,
                       const unsigned short* Whhb, const float* bhh,
                       float* state, unsigned short* stateb) {
    gemm(xlogb, LWb, Lb, logits, Nl, 1500);
    hipLaunchKernelGGL(rowops_kernel, dim3(Nl), blk, 0, stream, logits, cls, xlog, scaled,
                       cebuf + sidx * 8000, Nl);
    hipLaunchKernelGGL(spmv_scan, dim3(M), blk, 0, stream, adj, scaled, hbuf, hbufb, M, Nl);
    gemm(hbufb, Whhb, bhh, gh, M, 384);
    hipLaunchKernelGGL(gru_elem, dim3((M * 32 + 255) / 256), blk, 0, stream,
                       gi + giOff[sidx] * 384, gh, hbuf, state, stateb, M);
  };

  run_stage(0, featVb, feat_V, 3000, L00Wb, L00b, clsV, adj00, 8000, g0Whhb, g0_bhh, stP0, stP0b);
  run_stage(1, stP0b, stP0, 8000, L01Wb, L01b, clsP, adj01, 6000, g0Whhb, g0_bhh, stA0, stA0b);
  run_stage(2, featAb, feat_A, 6000, L10Wb, L10b, clsA, adj10, 8000, g1Whhb, g1_bhh, stP1, stP1b);
  run_stage(3, stP1b, stP1, 8000, L11Wb, L11b, clsP, adj11, 3000, g1Whhb, g1_bhh, stV1, stV1b);
  run_stage(4, stV1b, stV1, 3000, L12Wb, L12b, clsV, adj12, 1500, g1Whhb, g1_bhh, stC1, stC1b);

  // fused fuse-pipeline: 3 flat launches
  hipLaunchKernelGGL(fuse_scores_all, dim3((18500 + 3) / 4), blk, 0, stream,
                     selfb, stcat, W2, b2, W3, b3, s0b, s1b);
  hipLaunchKernelGGL(denom4, dim3(4), dim3(1024), 0, stream, s0b, s1b, den);
  hipLaunchKernelGGL(fuse_emb_all, dim3((18500 * 128 + 1536 + 255) / 256), blk, 0, stream,
                     selfb, stcat, s0b, s1b, den, rel_emb, fe, rel_out);

  hipLaunchKernelGGL(edge_both, dim3(2048), blk, 0, stream, u_d, u_s, fe, rel_emb, partial, 150000);

  hipLaunchKernelGGL(final_reduce, dim3(1), dim3(1024), 0, stream, partial, cebuf, out);
}

// Round 5
// 610.420 us; speedup vs baseline: 40.7283x; 1.0277x over previous
//
#include <hip/hip_runtime.h>
#include <cstdint>
#include <cstddef>

#define DEV_INLINE __device__ __forceinline__

typedef __attribute__((ext_vector_type(8))) short bf16x8;
typedef __attribute__((ext_vector_type(16))) float f32x16;
struct __align__(8) US4 { unsigned short u[4]; };

DEV_INLINE unsigned short f2bf(float x) {
  unsigned u = __float_as_uint(x);
  return (unsigned short)((u + 0x7FFFu + ((u >> 16) & 1u)) >> 16);
}

// ---------------------------------------------------------------------------
// Batched f32 -> bf16 conversion
// ---------------------------------------------------------------------------
struct CvtSeg { const float* src; unsigned short* dst; int n; int nblk; };
struct CvtArgs { CvtSeg seg[16]; int nseg; };

__global__ __launch_bounds__(256) void convert_bf16_many(CvtArgs args) {
  int b = blockIdx.x;
  int s = 0;
  while (s < args.nseg && b >= args.seg[s].nblk) { b -= args.seg[s].nblk; ++s; }
  if (s >= args.nseg) return;
  int base = b * 1024 + threadIdx.x * 4;
  if (base >= args.seg[s].n) return;
  float4 v = *reinterpret_cast<const float4*>(args.seg[s].src + base);
  US4 o;
  o.u[0] = f2bf(v.x); o.u[1] = f2bf(v.y); o.u[2] = f2bf(v.z); o.u[3] = f2bf(v.w);
  *reinterpret_cast<US4*>(args.seg[s].dst + base) = o;
}

// ---------------------------------------------------------------------------
// bf16 MFMA GEMM body: C[N,O] = Xb[N,128] @ Wb[O,128]^T + bias[O] (f32 out)
// ---------------------------------------------------------------------------
DEV_INLINE void gemm_body(
    const unsigned short* __restrict__ Xb, const unsigned short* __restrict__ Wb,
    const float* __restrict__ bias, float* __restrict__ C, int N, int O,
    int bm, int bn, unsigned short* Xs, unsigned short* Ws)
{
  const int tid = threadIdx.x;
#pragma unroll
  for (int i = 0; i < 8; ++i) {
    int s = tid + 256 * i;
    int row = s >> 4, c16 = s & 15;
    uint4 v = make_uint4(0, 0, 0, 0);
    int gr = bm + row;
    if (gr < N) v = *reinterpret_cast<const uint4*>(Xb + (size_t)gr * 128 + c16 * 8);
    *reinterpret_cast<uint4*>(&Xs[(row * 16 + (c16 ^ (row & 7))) * 8]) = v;
  }
#pragma unroll
  for (int i = 0; i < 4; ++i) {
    int s = tid + 256 * i;
    int row = s >> 4, c16 = s & 15;
    uint4 v = make_uint4(0, 0, 0, 0);
    int gw = bn + row;
    if (gw < O) v = *reinterpret_cast<const uint4*>(Wb + (size_t)gw * 128 + c16 * 8);
    *reinterpret_cast<uint4*>(&Ws[(row * 16 + (c16 ^ (row & 7))) * 8]) = v;
  }
  __syncthreads();

  const int wave = tid >> 6, lane = tid & 63;
  const int l31 = lane & 31, lhi = lane >> 5;

  f32x16 acc0, acc1;
#pragma unroll
  for (int i = 0; i < 16; ++i) { acc0[i] = 0.f; acc1[i] = 0.f; }

  const int ar = wave * 32 + l31;
#pragma unroll
  for (int ks = 0; ks < 8; ++ks) {
    int c16 = ks * 2 + lhi;
    bf16x8 a  = *reinterpret_cast<const bf16x8*>(&Xs[(ar * 16 + (c16 ^ (ar & 7))) * 8]);
    bf16x8 b0 = *reinterpret_cast<const bf16x8*>(&Ws[(l31 * 16 + (c16 ^ (l31 & 7))) * 8]);
    int br1 = 32 + l31;
    bf16x8 b1 = *reinterpret_cast<const bf16x8*>(&Ws[(br1 * 16 + (c16 ^ (br1 & 7))) * 8]);
    acc0 = __builtin_amdgcn_mfma_f32_32x32x16_bf16(a, b0, acc0, 0, 0, 0);
    acc1 = __builtin_amdgcn_mfma_f32_32x32x16_bf16(a, b1, acc1, 0, 0, 0);
  }

  // C/D layout: col = lane&31, row = (reg&3) + 8*(reg>>2) + 4*(lane>>5)
#pragma unroll
  for (int reg = 0; reg < 16; ++reg) {
    int r = bm + wave * 32 + (reg & 3) + 8 * (reg >> 2) + 4 * lhi;
    if (r < N) {
      int c0 = bn + l31;
      if (c0 < O) C[(size_t)r * O + c0] = acc0[reg] + bias[c0];
      int c1 = bn + 32 + l31;
      if (c1 < O) C[(size_t)r * O + c1] = acc1[reg] + bias[c1];
    }
  }
}

__global__ __launch_bounds__(256) void gemm_bf16(
    const unsigned short* __restrict__ Xb, const unsigned short* __restrict__ Wb,
    const float* __restrict__ bias, float* __restrict__ C, int N, int O)
{
  __shared__ __align__(16) unsigned short Xs[128 * 128];
  __shared__ __align__(16) unsigned short Ws[64 * 128];
  gemm_body(Xb, Wb, bias, C, N, O, blockIdx.x * 128, blockIdx.y * 64, Xs, Ws);
}

struct GemmSeg { const unsigned short* X; const unsigned short* W; const float* bias; float* C; int N; int blk0; };
struct GemmSegs { GemmSeg s[5]; int nseg; };

__global__ __launch_bounds__(256) void gemm_bf16_seg(GemmSegs segs, int O) {
  __shared__ __align__(16) unsigned short Xs[128 * 128];
  __shared__ __align__(16) unsigned short Ws[64 * 128];
  int bx = blockIdx.x;
  int si = 0;
  while (si + 1 < segs.nseg && bx >= segs.s[si + 1].blk0) ++si;
  const GemmSeg& sg = segs.s[si];
  gemm_body(sg.X, sg.W, sg.bias, sg.C, sg.N, O,
            (bx - sg.blk0) * 128, blockIdx.y * 64, Xs, Ws);
}

// ---------------------------------------------------------------------------
// Fused gh-GEMM + GRU: per 32-row block, 4 waves compute r/z/n col-slices.
// gh = Hb @ Whh^T (+bhh); state = (1-z)*n + z*h, written f32 + bf16.
// gi already contains x@Wih^T + bih.
// ---------------------------------------------------------------------------
__global__ __launch_bounds__(256) void gh_gru(
    const unsigned short* __restrict__ Hb, const unsigned short* __restrict__ Whhb,
    const float* __restrict__ bhh, const float* __restrict__ gi,
    const float* __restrict__ hv, float* __restrict__ out,
    unsigned short* __restrict__ outb, int M)
{
  __shared__ __align__(16) unsigned short As[32 * 128];  // 8 KB
  const int bm = blockIdx.x * 32;
  const int tid = threadIdx.x;
#pragma unroll
  for (int i = 0; i < 2; ++i) {
    int s = tid + 256 * i;           // 0..511
    int row = s >> 4, c16 = s & 15;
    uint4 v = make_uint4(0, 0, 0, 0);
    int gr = bm + row;
    if (gr < M) v = *reinterpret_cast<const uint4*>(Hb + (size_t)gr * 128 + c16 * 8);
    *reinterpret_cast<uint4*>(&As[(row * 16 + (c16 ^ (row & 7))) * 8]) = v;
  }
  __syncthreads();

  const int wave = tid >> 6, lane = tid & 63;
  const int l31 = lane & 31, lhi = lane >> 5;
  const int d = wave * 32 + l31;     // output col 0..127

  f32x16 ar, az, an;
#pragma unroll
  for (int i = 0; i < 16; ++i) { ar[i] = 0.f; az[i] = 0.f; an[i] = 0.f; }

#pragma unroll
  for (int ks = 0; ks < 8; ++ks) {
    int c16 = ks * 2 + lhi;
    bf16x8 a = *reinterpret_cast<const bf16x8*>(&As[(l31 * 16 + (c16 ^ (l31 & 7))) * 8]);
    const unsigned short* wb = Whhb + (size_t)c16 * 8;
    bf16x8 br = *reinterpret_cast<const bf16x8*>(wb + (size_t)d * 128);
    bf16x8 bz = *reinterpret_cast<const bf16x8*>(wb + (size_t)(128 + d) * 128);
    bf16x8 bn = *reinterpret_cast<const bf16x8*>(wb + (size_t)(256 + d) * 128);
    ar = __builtin_amdgcn_mfma_f32_32x32x16_bf16(a, br, ar, 0, 0, 0);
    az = __builtin_amdgcn_mfma_f32_32x32x16_bf16(a, bz, az, 0, 0, 0);
    an = __builtin_amdgcn_mfma_f32_32x32x16_bf16(a, bn, an, 0, 0, 0);
  }

  const float b_r = bhh[d], b_z = bhh[128 + d], b_n = bhh[256 + d];
#pragma unroll
  for (int reg = 0; reg < 16; ++reg) {
    int r = bm + (reg & 3) + 8 * (reg >> 2) + 4 * lhi;
    if (r < M) {
      const float* gir = gi + (size_t)r * 384;
      float rr = 1.f / (1.f + expf(-(gir[d] + ar[reg] + b_r)));
      float zz = 1.f / (1.f + expf(-(gir[128 + d] + az[reg] + b_z)));
      float nn = tanhf(gir[256 + d] + rr * (an[reg] + b_n));
      float h = hv[(size_t)r * 128 + d];
      float o = (1.f - zz) * nn + zz * h;
      out[(size_t)r * 128 + d] = o;
      outb[(size_t)r * 128 + d] = f2bf(o);
    }
  }
}

// ---------------------------------------------------------------------------
// Sparse row scan body (ballot over nonzeros)
// ---------------------------------------------------------------------------
DEV_INLINE void spmv_body(const float* __restrict__ A, const float* __restrict__ Xs,
                          float* __restrict__ H, unsigned short* __restrict__ Hb,
                          int row, int K, float (*red)[128])
{
  int tid = threadIdx.x, wave = tid >> 6, lane = tid & 63;
  const float4* Arow = reinterpret_cast<const float4*>(A + (size_t)row * K);
  int K4 = K >> 2;
  float acc0 = 0.f, acc1 = 0.f;
  for (int base = wave * 64; base < K4; base += 256) {
    int q = base + lane;
    float4 a = (q < K4) ? Arow[q] : make_float4(0.f, 0.f, 0.f, 0.f);
#pragma unroll
    for (int c = 0; c < 4; ++c) {
      float av = (c == 0) ? a.x : (c == 1) ? a.y : (c == 2) ? a.z : a.w;
      unsigned long long mm = __ballot(av != 0.f);
      while (mm) {
        int b = __builtin_ctzll(mm);
        mm &= mm - 1;
        float v = __shfl(av, b);
        int jj = (base + b) * 4 + c;
        const float* xr = Xs + (size_t)jj * 128;
        acc0 += v * xr[lane];
        acc1 += v * xr[lane + 64];
      }
    }
  }
  red[wave][lane] = acc0;
  red[wave][lane + 64] = acc1;
  __syncthreads();
  if (wave == 0) {
    float r0 = red[0][lane] + red[1][lane] + red[2][lane] + red[3][lane];
    float r1 = red[0][lane + 64] + red[1][lane + 64] + red[2][lane + 64] + red[3][lane + 64];
    H[(size_t)row * 128 + lane] = r0;
    H[(size_t)row * 128 + 64 + lane] = r1;
    Hb[(size_t)row * 128 + lane] = f2bf(r0);
    Hb[(size_t)row * 128 + 64 + lane] = f2bf(r1);
  }
}

__global__ __launch_bounds__(256) void spmv_scan(
    const float* __restrict__ A, const float* __restrict__ Xs,
    float* __restrict__ H, unsigned short* __restrict__ Hb, int M, int K)
{
  __shared__ float red[4][128];
  spmv_body(A, Xs, H, Hb, blockIdx.x, K, red);
}

// stages 0 and 2 merged (both static-input)
__global__ __launch_bounds__(256) void spmv_scan2(
    const float* __restrict__ A0, const float* __restrict__ X0,
    float* __restrict__ H0, unsigned short* __restrict__ H0b, int M0, int K0,
    const float* __restrict__ A1, const float* __restrict__ X1,
    float* __restrict__ H1, unsigned short* __restrict__ H1b, int K1)
{
  __shared__ float red[4][128];
  if ((int)blockIdx.x < M0) spmv_body(A0, X0, H0, H0b, blockIdx.x, K0, red);
  else                      spmv_body(A1, X1, H1, H1b, blockIdx.x - M0, K1, red);
}

// ---------------------------------------------------------------------------
// Wave-per-row softmax / CE (softmax-of-softmax, max(p)=1/Z1) / tcp scaling.
// 1500 cols = 6 float4/lane in registers; shfl-only reductions, no LDS/barriers.
// ---------------------------------------------------------------------------
DEV_INLINE void rowops_body(int lane, const float4* __restrict__ lr,
                            const float4* __restrict__ cr,
                            const float* __restrict__ srcrow,
                            float* __restrict__ scaledrow, float* __restrict__ cep)
{
  float4 e[6];
  float m = -3.4e38f;
#pragma unroll
  for (int k = 0; k < 6; ++k) {
    int idx = k * 64 + lane;
    if (idx < 375) {
      e[k] = lr[idx];
      m = fmaxf(m, fmaxf(fmaxf(e[k].x, e[k].y), fmaxf(e[k].z, e[k].w)));
    } else {
      e[k] = make_float4(-3.4e38f, -3.4e38f, -3.4e38f, -3.4e38f);
    }
  }
#pragma unroll
  for (int o = 1; o < 64; o <<= 1) m = fmaxf(m, __shfl_xor(m, o));
  float z = 0.f;
#pragma unroll
  for (int k = 0; k < 6; ++k) {
    e[k].x = expf(e[k].x - m); e[k].y = expf(e[k].y - m);
    e[k].z = expf(e[k].z - m); e[k].w = expf(e[k].w - m);
    z += (e[k].x + e[k].y) + (e[k].z + e[k].w);
  }
#pragma unroll
  for (int o = 1; o < 64; o <<= 1) z += __shfl_xor(z, o);
  float invZ1 = 1.0f / z;
  float m2 = invZ1;   // max(p) == 1/Z1 exactly
  float t = 0.f, ls = 0.f, z2 = 0.f;
#pragma unroll
  for (int k = 0; k < 6; ++k) {
    int idx = k * 64 + lane;
    if (idx < 375) {
      float4 c = cr[idx];
      float px = e[k].x * invZ1, py = e[k].y * invZ1;
      float pz = e[k].z * invZ1, pw = e[k].w * invZ1;
      t  += c.x * px + c.y * py + c.z * pz + c.w * pw;
      ls += (c.x + c.y) + (c.z + c.w);
      z2 += expf(px - m2) + expf(py - m2) + expf(pz - m2) + expf(pw - m2);
    }
  }
#pragma unroll
  for (int o = 1; o < 64; o <<= 1) {
    t += __shfl_xor(t, o); ls += __shfl_xor(ls, o); z2 += __shfl_xor(z2, o);
  }
  if (lane == 0) *cep = t - ls * (m2 + logf(z2));
  scaledrow[lane]      = t * srcrow[lane];
  scaledrow[lane + 64] = t * srcrow[lane + 64];
}

__global__ __launch_bounds__(256) void rowops_wave(
    const float* __restrict__ logits, const float* __restrict__ cls,
    const float* __restrict__ src, float* __restrict__ scaled,
    float* __restrict__ ce, int N)
{
  int gw = (blockIdx.x * 256 + threadIdx.x) >> 6;
  if (gw >= N) return;
  int lane = threadIdx.x & 63;
  rowops_body(lane,
              reinterpret_cast<const float4*>(logits + (size_t)gw * 1500),
              reinterpret_cast<const float4*>(cls + (size_t)gw * 1500),
              src + (size_t)gw * 128, scaled + (size_t)gw * 128, ce + gw);
}

// stages 0 (rows 0..2999) and 2 (rows 3000..8999) merged
__global__ __launch_bounds__(256) void rowops02(
    const float* __restrict__ lg0, const float* __restrict__ cls0,
    const float* __restrict__ src0, float* __restrict__ sc0, float* __restrict__ ce0,
    const float* __restrict__ lg2, const float* __restrict__ cls2,
    const float* __restrict__ src2, float* __restrict__ sc2, float* __restrict__ ce2)
{
  int gw = (blockIdx.x * 256 + threadIdx.x) >> 6;
  if (gw >= 9000) return;
  int lane = threadIdx.x & 63;
  if (gw < 3000) {
    rowops_body(lane,
                reinterpret_cast<const float4*>(lg0 + (size_t)gw * 1500),
                reinterpret_cast<const float4*>(cls0 + (size_t)gw * 1500),
                src0 + (size_t)gw * 128, sc0 + (size_t)gw * 128, ce0 + gw);
  } else {
    int r = gw - 3000;
    rowops_body(lane,
                reinterpret_cast<const float4*>(lg2 + (size_t)r * 1500),
                reinterpret_cast<const float4*>(cls2 + (size_t)r * 1500),
                src2 + (size_t)r * 128, sc2 + (size_t)r * 128, ce2 + r);
  }
}

// ---------------------------------------------------------------------------
// Fuse pipeline (flat over all 18500 entity rows)
// ---------------------------------------------------------------------------
__global__ __launch_bounds__(256) void fuse_scores_all(
    const float* __restrict__ e0, const float* __restrict__ e1,
    const float* __restrict__ W2, const float* __restrict__ b2,
    const float* __restrict__ W3, const float* __restrict__ b3,
    float* __restrict__ s0, float* __restrict__ s1)
{
  int lane = threadIdx.x & 63;
  int row = (blockIdx.x * 256 + threadIdx.x) >> 6;
  if (row >= 18500) return;
  float a0 = e0[(size_t)row * 128 + lane] * W2[lane] + e0[(size_t)row * 128 + 64 + lane] * W2[64 + lane];
  float a1 = e1[(size_t)row * 128 + lane] * W3[lane] + e1[(size_t)row * 128 + 64 + lane] * W3[64 + lane];
#pragma unroll
  for (int o = 32; o > 0; o >>= 1) { a0 += __shfl_down(a0, o); a1 += __shfl_down(a1, o); }
  if (lane == 0) {
    s0[row] = fmaxf(a0 + b2[0], 0.f);
    s1[row] = fmaxf(a1 + b3[0], 0.f);
  }
}

__global__ __launch_bounds__(1024) void denom4(
    const float* __restrict__ s0, const float* __restrict__ s1,
    float* __restrict__ den)
{
  __shared__ float red[1024];
  const int ns[4]   = {8000, 3000, 1500, 6000};
  const int offs[4] = {0, 8000, 11000, 12500};
  int b = blockIdx.x;
  int n = ns[b];
  const float* p0 = s0 + offs[b];
  const float* p1 = s1 + offs[b];
  int tid = threadIdx.x;
  float m = -3.4e38f;
  for (int i = tid; i < n; i += 1024) m = fmaxf(m, p0[i]);
  red[tid] = m; __syncthreads();
  for (int s = 512; s > 0; s >>= 1) { if (tid < s) red[tid] = fmaxf(red[tid], red[tid + s]); __syncthreads(); }
  float m0 = red[0]; __syncthreads();
  float z = 0.f;
  for (int i = tid; i < n; i += 1024) z += expf(p0[i] - m0);
  red[tid] = z; __syncthreads();
  for (int s = 512; s > 0; s >>= 1) { if (tid < s) red[tid] += red[tid + s]; __syncthreads(); }
  float Z0 = red[0]; __syncthreads();
  m = -3.4e38f;
  for (int i = tid; i < n; i += 1024) m = fmaxf(m, p1[i]);
  red[tid] = m; __syncthreads();
  for (int s = 512; s > 0; s >>= 1) { if (tid < s) red[tid] = fmaxf(red[tid], red[tid + s]); __syncthreads(); }
  float m1 = red[0]; __syncthreads();
  z = 0.f;
  for (int i = tid; i < n; i += 1024) z += expf(p1[i] - m1);
  red[tid] = z; __syncthreads();
  for (int s = 512; s > 0; s >>= 1) { if (tid < s) red[tid] += red[tid + s]; __syncthreads(); }
  if (tid == 0) { den[b * 4] = m0; den[b * 4 + 1] = Z0; den[b * 4 + 2] = m1; den[b * 4 + 3] = red[0]; }
}

__global__ __launch_bounds__(256) void fuse_emb_all(
    const float* __restrict__ e0, const float* __restrict__ e1,
    const float* __restrict__ s0, const float* __restrict__ s1,
    const float* __restrict__ den, const float* __restrict__ rel,
    float* __restrict__ fe, float* __restrict__ rel_out)
{
  int idx = blockIdx.x * 256 + threadIdx.x;
  const int tot = 18500 * 128;
  if (idx < tot) {
    int row = idx >> 7;
    int e = (row < 8000) ? 0 : (row < 11000) ? 1 : (row < 12500) ? 2 : 3;
    float a0 = expf(s0[row] - den[e * 4]) / den[e * 4 + 1];
    float a1 = expf(s1[row] - den[e * 4 + 2]) / den[e * 4 + 3];
    fe[idx] = fmaxf(a0 * e0[idx] + a1 * e1[idx], 0.f);
  } else if (idx < tot + 1536) {
    rel_out[idx - tot] = rel[idx - tot];
  }
}

// ---------------------------------------------------------------------------
// Edge losses (both sets in one launch)
// ---------------------------------------------------------------------------
__global__ __launch_bounds__(256) void edge_both(
    const int* __restrict__ ud, const int* __restrict__ us,
    const float* __restrict__ fe, const float* __restrict__ rel,
    float* __restrict__ partial, int En)
{
  int lane = threadIdx.x & 63;
  int wid = threadIdx.x >> 6;
  bool is_d = (blockIdx.x < 1024);
  int bb = is_d ? blockIdx.x : blockIdx.x - 1024;
  int gw = bb * 4 + wid;
  const int nw = 1024 * 4;
  float acc = 0.f;
  if (is_d) {
    for (int e = gw; e < En; e += nw) {
      int4 ei = *reinterpret_cast<const int4*>(ud + (size_t)e * 4);
      const float* fi = fe + (size_t)ei.x * 128;
      const float* fj = fe + (size_t)ei.y * 128;
      const float* rr = rel + (size_t)ei.w * 128;
      float t0 = tanhf(fi[lane] + fj[lane]);
      float t1 = tanhf(fi[lane + 64] + fj[lane + 64]);
      float d = rr[lane] * t0 + rr[lane + 64] * t1;
#pragma unroll
      for (int o = 32; o > 0; o >>= 1) d += __shfl_down(d, o);
      if (lane == 0) {
        float x = (float)ei.z * d;
        acc += (x >= 0.f) ? log1pf(expf(-x)) : (-x + log1pf(expf(x)));
      }
    }
  } else {
    for (int e = gw; e < En; e += nw) {
      int i = us[(size_t)e * 3], j = us[(size_t)e * 3 + 1], lab = us[(size_t)e * 3 + 2];
      const float* fi = fe + (size_t)i * 128;
      const float* fj = fe + (size_t)j * 128;
      float d = fi[lane] * fj[lane] + fi[lane + 64] * fj[lane + 64];
#pragma unroll
      for (int o = 32; o > 0; o >>= 1) d += __shfl_down(d, o);
      if (lane == 0) {
        float x = (float)lab * d;
        acc += (x >= 0.f) ? log1pf(expf(-x)) : (-x + log1pf(expf(x)));
      }
    }
  }
  __shared__ float red[4];
  if (lane == 0) red[wid] = acc;
  __syncthreads();
  if (threadIdx.x == 0) partial[blockIdx.x] = red[0] + red[1] + red[2] + red[3];
}

__global__ __launch_bounds__(1024) void final_reduce(
    const float* __restrict__ partial, const float* __restrict__ cebuf,
    float* __restrict__ out)
{
  __shared__ float red[1024];
  __shared__ float total;
  int tid = threadIdx.x;
  if (tid == 0) total = 0.f;
  __syncthreads();
  float a = partial[tid] + partial[tid + 1024];
  red[tid] = a; __syncthreads();
  for (int s = 512; s > 0; s >>= 1) { if (tid < s) red[tid] += red[tid + s]; __syncthreads(); }
  if (tid == 0) total += red[0];
  __syncthreads();
  const int ns[5] = {3000, 8000, 6000, 8000, 3000};
#pragma unroll
  for (int seg = 0; seg < 5; ++seg) {
    const float* v = cebuf + seg * 8000;
    float s = 0.f;
    for (int i = tid; i < ns[seg]; i += 1024) s += v[i];
    red[tid] = s; __syncthreads();
    for (int st = 512; st > 0; st >>= 1) { if (tid < st) red[tid] += red[tid + st]; __syncthreads(); }
    if (tid == 0) total -= red[0] / (float)ns[seg];
    __syncthreads();
  }
  if (tid == 0) out[0] = total;
}

// ---------------------------------------------------------------------------
extern "C" void kernel_launch(void* const* d_in, const int* in_sizes, int n_in,
                              void* d_out, int out_size, void* d_ws, size_t ws_size,
                              hipStream_t stream)
{
  const float* feat_P = (const float*)d_in[0];
  const float* feat_V = (const float*)d_in[1];
  const float* feat_C = (const float*)d_in[2];
  const float* feat_A = (const float*)d_in[3];
  const float* W1 = (const float*)d_in[4];
  const float* b1 = (const float*)d_in[5];
  const float* W2 = (const float*)d_in[6];
  const float* b2 = (const float*)d_in[7];
  const float* W3 = (const float*)d_in[8];
  const float* b3 = (const float*)d_in[9];
  const float* L00W = (const float*)d_in[10];
  const float* L00b = (const float*)d_in[11];
  const float* L01W = (const float*)d_in[12];
  const float* L01b = (const float*)d_in[13];
  const float* L10W = (const float*)d_in[14];
  const float* L10b = (const float*)d_in[15];
  const float* L11W = (const float*)d_in[16];
  const float* L11b = (const float*)d_in[17];
  const float* L12W = (const float*)d_in[18];
  const float* L12b = (const float*)d_in[19];
  const float* g0_Wih = (const float*)d_in[20];
  const float* g0_Whh = (const float*)d_in[21];
  const float* g0_bih = (const float*)d_in[22];
  const float* g0_bhh = (const float*)d_in[23];
  const float* g1_Wih = (const float*)d_in[24];
  const float* g1_Whh = (const float*)d_in[25];
  const float* g1_bih = (const float*)d_in[26];
  const float* g1_bhh = (const float*)d_in[27];
  const float* rel_emb = (const float*)d_in[28];
  const float* adj00 = (const float*)d_in[29];
  const float* adj01 = (const float*)d_in[30];
  const float* adj10 = (const float*)d_in[31];
  const float* adj11 = (const float*)d_in[32];
  const float* adj12 = (const float*)d_in[33];
  const float* clsA = (const float*)d_in[34];
  const float* clsP = (const float*)d_in[35];
  const float* clsV = (const float*)d_in[36];
  const int* u_s = (const int*)d_in[37];
  const int* u_d = (const int*)d_in[38];

  float* out = (float*)d_out;
  float* fe = out + 1;
  float* rel_out = out + 1 + 18500 * 128;

  float* ws = (float*)d_ws;
  size_t o = 0;
  auto alloc = [&](size_t n) { float* p = ws + o; o += n; return p; };
  float* selfb   = alloc((size_t)18500 * 128);
  float* stcat   = alloc((size_t)18500 * 128);   // P0|V1|C1|A0
  float* stP1    = alloc((size_t)8000 * 128);
  float* gi      = alloc((size_t)26500 * 384);
  float* logits  = alloc((size_t)8000 * 1500);   // chain stages 1/3/4
  float* logits0 = alloc((size_t)3000 * 1500);
  float* logits2 = alloc((size_t)6000 * 1500);
  float* scaled  = alloc((size_t)8000 * 128);
  float* scaled0 = alloc((size_t)3000 * 128);
  float* scaled2 = alloc((size_t)6000 * 128);
  float* h0      = alloc((size_t)8000 * 128);
  float* h2      = alloc((size_t)8000 * 128);
  float* hbuf    = alloc((size_t)8000 * 128);
  float* cebuf   = alloc(5 * 8000);
  float* s0b = alloc(18500);
  float* s1b = alloc(18500);
  float* den = alloc(16);
  float* partial = alloc(2048);
  auto allocb = [&](size_t nelem) { unsigned short* p = (unsigned short*)(ws + o); o += nelem / 2; return p; };
  unsigned short* featb  = allocb((size_t)18500 * 128);
  unsigned short* stcatb = allocb((size_t)18500 * 128);
  unsigned short* stP1b  = allocb((size_t)8000 * 128);
  unsigned short* h0b    = allocb((size_t)8000 * 128);
  unsigned short* h2b    = allocb((size_t)8000 * 128);
  unsigned short* hbufb  = allocb((size_t)8000 * 128);
  unsigned short* W1b = allocb(128 * 128);
  unsigned short* L00Wb = allocb(1500 * 128);
  unsigned short* L01Wb = allocb(1500 * 128);
  unsigned short* L10Wb = allocb(1500 * 128);
  unsigned short* L11Wb = allocb(1500 * 128);
  unsigned short* L12Wb = allocb(1500 * 128);
  unsigned short* g0Wihb = allocb(384 * 128);
  unsigned short* g0Whhb = allocb(384 * 128);
  unsigned short* g1Wihb = allocb(384 * 128);
  unsigned short* g1Whhb = allocb(384 * 128);
  unsigned short* featPb = featb;
  unsigned short* featVb = featb + (size_t)8000 * 128;
  unsigned short* featCb = featb + (size_t)11000 * 128;
  unsigned short* featAb = featb + (size_t)12500 * 128;
  float* stP0 = stcat;
  float* stV1 = stcat + (size_t)8000 * 128;
  float* stC1 = stcat + (size_t)11000 * 128;
  float* stA0 = stcat + (size_t)12500 * 128;
  unsigned short* stP0b = stcatb;
  unsigned short* stV1b = stcatb + (size_t)8000 * 128;
  unsigned short* stC1b = stcatb + (size_t)11000 * 128;
  unsigned short* stA0b = stcatb + (size_t)12500 * 128;
  (void)ws_size; (void)in_sizes; (void)n_in; (void)out_size;

  dim3 blk(256);

  // --- batched f32->bf16 conversion ---
  CvtArgs ca{};
  int nseg = 0, totblk = 0;
  auto addseg = [&](const float* src, unsigned short* dst, int n) {
    ca.seg[nseg].src = src; ca.seg[nseg].dst = dst; ca.seg[nseg].n = n;
    ca.seg[nseg].nblk = (n + 1023) / 1024; totblk += ca.seg[nseg].nblk; ++nseg;
  };
  addseg(feat_P, featPb, 8000 * 128);
  addseg(feat_V, featVb, 3000 * 128);
  addseg(feat_C, featCb, 1500 * 128);
  addseg(feat_A, featAb, 6000 * 128);
  addseg(W1, W1b, 128 * 128);
  addseg(L00W, L00Wb, 1500 * 128);
  addseg(L01W, L01Wb, 1500 * 128);
  addseg(L10W, L10Wb, 1500 * 128);
  addseg(L11W, L11Wb, 1500 * 128);
  addseg(L12W, L12Wb, 1500 * 128);
  addseg(g0_Wih, g0Wihb, 384 * 128);
  addseg(g0_Whh, g0Whhb, 384 * 128);
  addseg(g1_Wih, g1Wihb, 384 * 128);
  addseg(g1_Whh, g1Whhb, 384 * 128);
  ca.nseg = nseg;
  hipLaunchKernelGGL(convert_bf16_many, dim3(totblk), blk, 0, stream, ca);

  auto gemm = [&](const unsigned short* Xb, const unsigned short* Wb,
                  const float* b, float* C, int N, int O) {
    dim3 g((N + 127) / 128, (O + 63) / 64);
    hipLaunchKernelGGL(gemm_bf16, g, blk, 0, stream, Xb, Wb, b, C, N, O);
  };

  // self embeddings
  gemm(featb, W1b, b1, selfb, 18500, 128);

  // all 5 gi GEMMs in one launch (O=384)
  const int giM[5] = {8000, 6000, 8000, 3000, 1500};
  const size_t giOff[5] = {0, 8000, 14000, 22000, 25000};
  {
    GemmSegs gs{};
    const unsigned short* gx[5] = {featPb, featAb, featPb, featVb, featCb};
    const unsigned short* gw[5] = {g0Wihb, g0Wihb, g1Wihb, g1Wihb, g1Wihb};
    const float* gbias[5] = {g0_bih, g0_bih, g1_bih, g1_bih, g1_bih};
    int blk0 = 0;
    for (int s = 0; s < 5; ++s) {
      gs.s[s].X = gx[s]; gs.s[s].W = gw[s]; gs.s[s].bias = gbias[s];
      gs.s[s].C = gi + giOff[s] * 384; gs.s[s].N = giM[s]; gs.s[s].blk0 = blk0;
      blk0 += (giM[s] + 127) / 128;
    }
    gs.nseg = 5;
    hipLaunchKernelGGL(gemm_bf16_seg, dim3(blk0, 6), blk, 0, stream, gs, 384);
  }

  // static logits for stages 0 and 2 in one launch (O=1500)
  {
    GemmSegs gs{};
    gs.s[0] = GemmSeg{featVb, L00Wb, L00b, logits0, 3000, 0};
    gs.s[1] = GemmSeg{featAb, L10Wb, L10b, logits2, 6000, (3000 + 127) / 128};
    gs.nseg = 2;
    int nb = gs.s[1].blk0 + (6000 + 127) / 128;
    hipLaunchKernelGGL(gemm_bf16_seg, dim3(nb, 24), blk, 0, stream, gs, 1500);
  }

  // rowops + spmv for stages 0 and 2 (merged)
  hipLaunchKernelGGL(rowops02, dim3((9000 * 64 + 255) / 256), blk, 0, stream,
                     logits0, clsV, feat_V, scaled0, cebuf + 0 * 8000,
                     logits2, clsA, feat_A, scaled2, cebuf + 2 * 8000);
  hipLaunchKernelGGL(spmv_scan2, dim3(16000), blk, 0, stream,
                     adj00, scaled0, h0, h0b, 8000, 3000,
                     adj10, scaled2, h2, h2b, 6000);

  auto ghgru = [&](const unsigned short* Hb, const unsigned short* Whhb, const float* bhh,
                   int sidx, const float* hv, float* st, unsigned short* stb, int M) {
    hipLaunchKernelGGL(gh_gru, dim3((M + 31) / 32), blk, 0, stream,
                       Hb, Whhb, bhh, gi + giOff[sidx] * 384, hv, st, stb, M);
  };

  // stage 0 tail
  ghgru(h0b, g0Whhb, g0_bhh, 0, h0, stP0, stP0b, 8000);
  // stage 1
  gemm(stP0b, L01Wb, L01b, logits, 8000, 1500);
  hipLaunchKernelGGL(rowops_wave, dim3((8000 * 64 + 255) / 256), blk, 0, stream,
                     logits, clsP, stP0, scaled, cebuf + 1 * 8000, 8000);
  hipLaunchKernelGGL(spmv_scan, dim3(6000), blk, 0, stream, adj01, scaled, hbuf, hbufb, 6000, 8000);
  ghgru(hbufb, g0Whhb, g0_bhh, 1, hbuf, stA0, stA0b, 6000);
  // stage 2 tail
  ghgru(h2b, g1Whhb, g1_bhh, 2, h2, stP1, stP1b, 8000);
  // stage 3
  gemm(stP1b, L11Wb, L11b, logits, 8000, 1500);
  hipLaunchKernelGGL(rowops_wave, dim3((8000 * 64 + 255) / 256), blk, 0, stream,
                     logits, clsP, stP1, scaled, cebuf + 3 * 8000, 8000);
  hipLaunchKernelGGL(spmv_scan, dim3(3000), blk, 0, stream, adj11, scaled, hbuf, hbufb, 3000, 8000);
  ghgru(hbufb, g1Whhb, g1_bhh, 3, hbuf, stV1, stV1b, 3000);
  // stage 4
  gemm(stV1b, L12Wb, L12b, logits, 3000, 1500);
  hipLaunchKernelGGL(rowops_wave, dim3((3000 * 64 + 255) / 256), blk, 0, stream,
                     logits, clsV, stV1, scaled, cebuf + 4 * 8000, 3000);
  hipLaunchKernelGGL(spmv_scan, dim3(1500), blk, 0, stream, adj12, scaled, hbuf, hbufb, 1500, 3000);
  ghgru(hbufb, g1Whhb, g1_bhh, 4, hbuf, stC1, stC1b, 1500);

  // fuse pipeline
  hipLaunchKernelGGL(fuse_scores_all, dim3((18500 + 3) / 4), blk, 0, stream,
                     selfb, stcat, W2, b2, W3, b3, s0b, s1b);
  hipLaunchKernelGGL(denom4, dim3(4), dim3(1024), 0, stream, s0b, s1b, den);
  hipLaunchKernelGGL(fuse_emb_all, dim3((18500 * 128 + 1536 + 255) / 256), blk, 0, stream,
                     selfb, stcat, s0b, s1b, den, rel_emb, fe, rel_out);

  hipLaunchKernelGGL(edge_both, dim3(2048), blk, 0, stream, u_d, u_s, fe, rel_emb, partial, 150000);

  hipLaunchKernelGGL(final_reduce, dim3(1), dim3(1024), 0, stream, partial, cebuf, out);
}

// Round 6
// 555.368 us; speedup vs baseline: 44.7655x; 1.0991x over previous
//
#include <hip/hip_runtime.h>
#include <cstdint>
#include <cstddef>

#define DEV_INLINE __device__ __forceinline__

typedef __attribute__((ext_vector_type(8))) short bf16x8;
typedef __attribute__((ext_vector_type(16))) float f32x16;
struct __align__(8) US4 { unsigned short u[4]; };

DEV_INLINE unsigned short f2bf(float x) {
  unsigned u = __float_as_uint(x);
  return (unsigned short)((u + 0x7FFFu + ((u >> 16) & 1u)) >> 16);
}
DEV_INLINE float2 bfpair(unsigned v) {
  return make_float2(__uint_as_float(v << 16), __uint_as_float(v & 0xFFFF0000u));
}

// ---------------------------------------------------------------------------
// Batched f32 -> bf16 conversion
// ---------------------------------------------------------------------------
struct CvtSeg { const float* src; unsigned short* dst; int n; int nblk; };
struct CvtArgs { CvtSeg seg[16]; int nseg; };

__global__ __launch_bounds__(256) void convert_bf16_many(CvtArgs args) {
  int b = blockIdx.x;
  int s = 0;
  while (s < args.nseg && b >= args.seg[s].nblk) { b -= args.seg[s].nblk; ++s; }
  if (s >= args.nseg) return;
  int base = b * 1024 + threadIdx.x * 4;
  if (base >= args.seg[s].n) return;
  float4 v = *reinterpret_cast<const float4*>(args.seg[s].src + base);
  US4 o;
  o.u[0] = f2bf(v.x); o.u[1] = f2bf(v.y); o.u[2] = f2bf(v.z); o.u[3] = f2bf(v.w);
  *reinterpret_cast<US4*>(args.seg[s].dst + base) = o;
}

// ---------------------------------------------------------------------------
// bf16 MFMA GEMM body: C[N,O] = Xb[N,128] @ Wb[O,128]^T + bias[O] (f32 out)
// Block 256 thr = 4 waves; tile 128(M)x64(N); XOR-swizzled LDS.
// ---------------------------------------------------------------------------
DEV_INLINE void gemm_body(
    const unsigned short* __restrict__ Xb, const unsigned short* __restrict__ Wb,
    const float* __restrict__ bias, float* __restrict__ C, int N, int O,
    int bm, int bn, unsigned short* Xs, unsigned short* Ws)
{
  const int tid = threadIdx.x;
#pragma unroll
  for (int i = 0; i < 8; ++i) {
    int s = tid + 256 * i;
    int row = s >> 4, c16 = s & 15;
    uint4 v = make_uint4(0, 0, 0, 0);
    int gr = bm + row;
    if (gr < N) v = *reinterpret_cast<const uint4*>(Xb + (size_t)gr * 128 + c16 * 8);
    *reinterpret_cast<uint4*>(&Xs[(row * 16 + (c16 ^ (row & 7))) * 8]) = v;
  }
#pragma unroll
  for (int i = 0; i < 4; ++i) {
    int s = tid + 256 * i;
    int row = s >> 4, c16 = s & 15;
    uint4 v = make_uint4(0, 0, 0, 0);
    int gw = bn + row;
    if (gw < O) v = *reinterpret_cast<const uint4*>(Wb + (size_t)gw * 128 + c16 * 8);
    *reinterpret_cast<uint4*>(&Ws[(row * 16 + (c16 ^ (row & 7))) * 8]) = v;
  }
  __syncthreads();

  const int wave = tid >> 6, lane = tid & 63;
  const int l31 = lane & 31, lhi = lane >> 5;

  f32x16 acc0, acc1;
#pragma unroll
  for (int i = 0; i < 16; ++i) { acc0[i] = 0.f; acc1[i] = 0.f; }

  const int ar = wave * 32 + l31;
#pragma unroll
  for (int ks = 0; ks < 8; ++ks) {
    int c16 = ks * 2 + lhi;
    bf16x8 a  = *reinterpret_cast<const bf16x8*>(&Xs[(ar * 16 + (c16 ^ (ar & 7))) * 8]);
    bf16x8 b0 = *reinterpret_cast<const bf16x8*>(&Ws[(l31 * 16 + (c16 ^ (l31 & 7))) * 8]);
    int br1 = 32 + l31;
    bf16x8 b1 = *reinterpret_cast<const bf16x8*>(&Ws[(br1 * 16 + (c16 ^ (br1 & 7))) * 8]);
    acc0 = __builtin_amdgcn_mfma_f32_32x32x16_bf16(a, b0, acc0, 0, 0, 0);
    acc1 = __builtin_amdgcn_mfma_f32_32x32x16_bf16(a, b1, acc1, 0, 0, 0);
  }

  // C/D layout: col = lane&31, row = (reg&3) + 8*(reg>>2) + 4*(lane>>5)
#pragma unroll
  for (int reg = 0; reg < 16; ++reg) {
    int r = bm + wave * 32 + (reg & 3) + 8 * (reg >> 2) + 4 * lhi;
    if (r < N) {
      int c0 = bn + l31;
      if (c0 < O) C[(size_t)r * O + c0] = acc0[reg] + bias[c0];
      int c1 = bn + 32 + l31;
      if (c1 < O) C[(size_t)r * O + c1] = acc1[reg] + bias[c1];
    }
  }
}

__global__ __launch_bounds__(256) void gemm_bf16(
    const unsigned short* __restrict__ Xb, const unsigned short* __restrict__ Wb,
    const float* __restrict__ bias, float* __restrict__ C, int N, int O)
{
  __shared__ __align__(16) unsigned short Xs[128 * 128];
  __shared__ __align__(16) unsigned short Ws[64 * 128];
  gemm_body(Xb, Wb, bias, C, N, O, blockIdx.x * 128, blockIdx.y * 64, Xs, Ws);
}

// Generalized multi-segment GEMM: per-seg N, O, 1D grid (x-major within seg)
struct GSeg { const unsigned short* X; const unsigned short* W; const float* bias;
              float* C; int N; int O; int blk0; int xblk; };
struct GSegs { GSeg s[8]; int nseg; };

__global__ __launch_bounds__(256) void gemm_bf16_gseg(GSegs gs) {
  __shared__ __align__(16) unsigned short Xs[128 * 128];
  __shared__ __align__(16) unsigned short Ws[64 * 128];
  int bx = blockIdx.x;
  int si = 0;
  while (si + 1 < gs.nseg && bx >= gs.s[si + 1].blk0) ++si;
  const GSeg& g = gs.s[si];
  int b = bx - g.blk0;
  int bm = (b % g.xblk) * 128;
  int bn = (b / g.xblk) * 64;
  gemm_body(g.X, g.W, g.bias, g.C, g.N, g.O, bm, bn, Xs, Ws);
}

// ---------------------------------------------------------------------------
// Fused gh-GEMM + GRU body
// ---------------------------------------------------------------------------
DEV_INLINE void ghgru_body(
    const unsigned short* __restrict__ Hb, const unsigned short* __restrict__ Whhb,
    const float* __restrict__ bhh, const float* __restrict__ gi,
    const float* __restrict__ hv, float* __restrict__ out,
    unsigned short* __restrict__ outb, int M, int bm, unsigned short* As)
{
  const int tid = threadIdx.x;
#pragma unroll
  for (int i = 0; i < 2; ++i) {
    int s = tid + 256 * i;
    int row = s >> 4, c16 = s & 15;
    uint4 v = make_uint4(0, 0, 0, 0);
    int gr = bm + row;
    if (gr < M) v = *reinterpret_cast<const uint4*>(Hb + (size_t)gr * 128 + c16 * 8);
    *reinterpret_cast<uint4*>(&As[(row * 16 + (c16 ^ (row & 7))) * 8]) = v;
  }
  __syncthreads();

  const int wave = tid >> 6, lane = tid & 63;
  const int l31 = lane & 31, lhi = lane >> 5;
  const int d = wave * 32 + l31;

  f32x16 ar, az, an;
#pragma unroll
  for (int i = 0; i < 16; ++i) { ar[i] = 0.f; az[i] = 0.f; an[i] = 0.f; }

#pragma unroll
  for (int ks = 0; ks < 8; ++ks) {
    int c16 = ks * 2 + lhi;
    bf16x8 a = *reinterpret_cast<const bf16x8*>(&As[(l31 * 16 + (c16 ^ (l31 & 7))) * 8]);
    const unsigned short* wb = Whhb + (size_t)c16 * 8;
    bf16x8 br = *reinterpret_cast<const bf16x8*>(wb + (size_t)d * 128);
    bf16x8 bz = *reinterpret_cast<const bf16x8*>(wb + (size_t)(128 + d) * 128);
    bf16x8 bn = *reinterpret_cast<const bf16x8*>(wb + (size_t)(256 + d) * 128);
    ar = __builtin_amdgcn_mfma_f32_32x32x16_bf16(a, br, ar, 0, 0, 0);
    az = __builtin_amdgcn_mfma_f32_32x32x16_bf16(a, bz, az, 0, 0, 0);
    an = __builtin_amdgcn_mfma_f32_32x32x16_bf16(a, bn, an, 0, 0, 0);
  }

  const float b_r = bhh[d], b_z = bhh[128 + d], b_n = bhh[256 + d];
#pragma unroll
  for (int reg = 0; reg < 16; ++reg) {
    int r = bm + (reg & 3) + 8 * (reg >> 2) + 4 * lhi;
    if (r < M) {
      const float* gir = gi + (size_t)r * 384;
      float rr = 1.f / (1.f + expf(-(gir[d] + ar[reg] + b_r)));
      float zz = 1.f / (1.f + expf(-(gir[128 + d] + az[reg] + b_z)));
      float nn = tanhf(gir[256 + d] + rr * (an[reg] + b_n));
      float h = hv[(size_t)r * 128 + d];
      float o = (1.f - zz) * nn + zz * h;
      out[(size_t)r * 128 + d] = o;
      outb[(size_t)r * 128 + d] = f2bf(o);
    }
  }
}

__global__ __launch_bounds__(256) void gh_gru(
    const unsigned short* __restrict__ Hb, const unsigned short* __restrict__ Whhb,
    const float* __restrict__ bhh, const float* __restrict__ gi,
    const float* __restrict__ hv, float* __restrict__ out,
    unsigned short* __restrict__ outb, int M)
{
  __shared__ __align__(16) unsigned short As[32 * 128];
  ghgru_body(Hb, Whhb, bhh, gi, hv, out, outb, M, blockIdx.x * 32, As);
}

// two independent gh_gru problems in one launch
__global__ __launch_bounds__(256) void gh_gru2(
    const unsigned short* Hb0, const unsigned short* Whh0, const float* bhh0,
    const float* gi0, const float* hv0, float* out0, unsigned short* outb0,
    int M0, int nblk0,
    const unsigned short* Hb1, const unsigned short* Whh1, const float* bhh1,
    const float* gi1, const float* hv1, float* out1, unsigned short* outb1, int M1)
{
  __shared__ __align__(16) unsigned short As[32 * 128];
  if ((int)blockIdx.x < nblk0)
    ghgru_body(Hb0, Whh0, bhh0, gi0, hv0, out0, outb0, M0, blockIdx.x * 32, As);
  else
    ghgru_body(Hb1, Whh1, bhh1, gi1, hv1, out1, outb1, M1, (blockIdx.x - nblk0) * 32, As);
}

// ---------------------------------------------------------------------------
// Sparse row scan (ballot over nonzeros)
// ---------------------------------------------------------------------------
DEV_INLINE void spmv_body(const float* __restrict__ A, const float* __restrict__ Xs,
                          float* __restrict__ H, unsigned short* __restrict__ Hb,
                          int row, int K, float (*red)[128])
{
  int tid = threadIdx.x, wave = tid >> 6, lane = tid & 63;
  const float4* Arow = reinterpret_cast<const float4*>(A + (size_t)row * K);
  int K4 = K >> 2;
  float acc0 = 0.f, acc1 = 0.f;
  for (int base = wave * 64; base < K4; base += 256) {
    int q = base + lane;
    float4 a = (q < K4) ? Arow[q] : make_float4(0.f, 0.f, 0.f, 0.f);
#pragma unroll
    for (int c = 0; c < 4; ++c) {
      float av = (c == 0) ? a.x : (c == 1) ? a.y : (c == 2) ? a.z : a.w;
      unsigned long long mm = __ballot(av != 0.f);
      while (mm) {
        int b = __builtin_ctzll(mm);
        mm &= mm - 1;
        float v = __shfl(av, b);
        int jj = (base + b) * 4 + c;
        const float* xr = Xs + (size_t)jj * 128;
        acc0 += v * xr[lane];
        acc1 += v * xr[lane + 64];
      }
    }
  }
  red[wave][lane] = acc0;
  red[wave][lane + 64] = acc1;
  __syncthreads();
  if (wave == 0) {
    float r0 = red[0][lane] + red[1][lane] + red[2][lane] + red[3][lane];
    float r1 = red[0][lane + 64] + red[1][lane + 64] + red[2][lane + 64] + red[3][lane + 64];
    H[(size_t)row * 128 + lane] = r0;
    H[(size_t)row * 128 + 64 + lane] = r1;
    Hb[(size_t)row * 128 + lane] = f2bf(r0);
    Hb[(size_t)row * 128 + 64 + lane] = f2bf(r1);
  }
}

__global__ __launch_bounds__(256) void spmv_scan(
    const float* __restrict__ A, const float* __restrict__ Xs,
    float* __restrict__ H, unsigned short* __restrict__ Hb, int M, int K)
{
  __shared__ float red[4][128];
  spmv_body(A, Xs, H, Hb, blockIdx.x, K, red);
}

__global__ __launch_bounds__(256) void spmv_scan2(
    const float* __restrict__ A0, const float* __restrict__ X0,
    float* __restrict__ H0, unsigned short* __restrict__ H0b, int M0, int K0,
    const float* __restrict__ A1, const float* __restrict__ X1,
    float* __restrict__ H1, unsigned short* __restrict__ H1b, int K1)
{
  __shared__ float red[4][128];
  if ((int)blockIdx.x < M0) spmv_body(A0, X0, H0, H0b, blockIdx.x, K0, red);
  else                      spmv_body(A1, X1, H1, H1b, blockIdx.x - M0, K1, red);
}

// ---------------------------------------------------------------------------
// Wave-per-row softmax / CE (softmax-of-softmax, max(p)=1/Z1) / tcp scaling.
// ---------------------------------------------------------------------------
DEV_INLINE void rowops_body(int lane, const float4* __restrict__ lr,
                            const float4* __restrict__ cr,
                            const float* __restrict__ srcrow,
                            float* __restrict__ scaledrow, float* __restrict__ cep)
{
  float4 e[6];
  float m = -3.4e38f;
#pragma unroll
  for (int k = 0; k < 6; ++k) {
    int idx = k * 64 + lane;
    if (idx < 375) {
      e[k] = lr[idx];
      m = fmaxf(m, fmaxf(fmaxf(e[k].x, e[k].y), fmaxf(e[k].z, e[k].w)));
    } else {
      e[k] = make_float4(-3.4e38f, -3.4e38f, -3.4e38f, -3.4e38f);
    }
  }
#pragma unroll
  for (int o = 1; o < 64; o <<= 1) m = fmaxf(m, __shfl_xor(m, o));
  float z = 0.f;
#pragma unroll
  for (int k = 0; k < 6; ++k) {
    e[k].x = expf(e[k].x - m); e[k].y = expf(e[k].y - m);
    e[k].z = expf(e[k].z - m); e[k].w = expf(e[k].w - m);
    z += (e[k].x + e[k].y) + (e[k].z + e[k].w);
  }
#pragma unroll
  for (int o = 1; o < 64; o <<= 1) z += __shfl_xor(z, o);
  float invZ1 = 1.0f / z;
  float m2 = invZ1;
  float t = 0.f, ls = 0.f, z2 = 0.f;
#pragma unroll
  for (int k = 0; k < 6; ++k) {
    int idx = k * 64 + lane;
    if (idx < 375) {
      float4 c = cr[idx];
      float px = e[k].x * invZ1, py = e[k].y * invZ1;
      float pz = e[k].z * invZ1, pw = e[k].w * invZ1;
      t  += c.x * px + c.y * py + c.z * pz + c.w * pw;
      ls += (c.x + c.y) + (c.z + c.w);
      z2 += expf(px - m2) + expf(py - m2) + expf(pz - m2) + expf(pw - m2);
    }
  }
#pragma unroll
  for (int o = 1; o < 64; o <<= 1) {
    t += __shfl_xor(t, o); ls += __shfl_xor(ls, o); z2 += __shfl_xor(z2, o);
  }
  if (lane == 0) *cep = t - ls * (m2 + logf(z2));
  scaledrow[lane]      = t * srcrow[lane];
  scaledrow[lane + 64] = t * srcrow[lane + 64];
}

__global__ __launch_bounds__(256) void rowops_wave(
    const float* __restrict__ logits, const float* __restrict__ cls,
    const float* __restrict__ src, float* __restrict__ scaled,
    float* __restrict__ ce, int N)
{
  int gw = (blockIdx.x * 256 + threadIdx.x) >> 6;
  if (gw >= N) return;
  int lane = threadIdx.x & 63;
  rowops_body(lane,
              reinterpret_cast<const float4*>(logits + (size_t)gw * 1500),
              reinterpret_cast<const float4*>(cls + (size_t)gw * 1500),
              src + (size_t)gw * 128, scaled + (size_t)gw * 128, ce + gw);
}

// two independent rowops problems in one launch
__global__ __launch_bounds__(256) void rowops2(
    const float* lgA, const float* clsA_, const float* srcA, float* scA, float* ceA, int nA,
    const float* lgB, const float* clsB_, const float* srcB, float* scB, float* ceB, int nB)
{
  int gw = (blockIdx.x * 256 + threadIdx.x) >> 6;
  if (gw >= nA + nB) return;
  int lane = threadIdx.x & 63;
  if (gw < nA) {
    rowops_body(lane,
                reinterpret_cast<const float4*>(lgA + (size_t)gw * 1500),
                reinterpret_cast<const float4*>(clsA_ + (size_t)gw * 1500),
                srcA + (size_t)gw * 128, scA + (size_t)gw * 128, ceA + gw);
  } else {
    int r = gw - nA;
    rowops_body(lane,
                reinterpret_cast<const float4*>(lgB + (size_t)r * 1500),
                reinterpret_cast<const float4*>(clsB_ + (size_t)r * 1500),
                srcB + (size_t)r * 128, scB + (size_t)r * 128, ceB + r);
  }
}

// ---------------------------------------------------------------------------
// Fuse pipeline
// ---------------------------------------------------------------------------
__global__ __launch_bounds__(256) void fuse_scores_all(
    const float* __restrict__ e0, const float* __restrict__ e1,
    const float* __restrict__ W2, const float* __restrict__ b2,
    const float* __restrict__ W3, const float* __restrict__ b3,
    float* __restrict__ s0, float* __restrict__ s1)
{
  int lane = threadIdx.x & 63;
  int row = (blockIdx.x * 256 + threadIdx.x) >> 6;
  if (row >= 18500) return;
  float a0 = e0[(size_t)row * 128 + lane] * W2[lane] + e0[(size_t)row * 128 + 64 + lane] * W2[64 + lane];
  float a1 = e1[(size_t)row * 128 + lane] * W3[lane] + e1[(size_t)row * 128 + 64 + lane] * W3[64 + lane];
#pragma unroll
  for (int o = 32; o > 0; o >>= 1) { a0 += __shfl_down(a0, o); a1 += __shfl_down(a1, o); }
  if (lane == 0) {
    s0[row] = fmaxf(a0 + b2[0], 0.f);
    s1[row] = fmaxf(a1 + b3[0], 0.f);
  }
}

__global__ __launch_bounds__(1024) void denom4(
    const float* __restrict__ s0, const float* __restrict__ s1,
    float* __restrict__ den)
{
  __shared__ float red[1024];
  const int ns[4]   = {8000, 3000, 1500, 6000};
  const int offs[4] = {0, 8000, 11000, 12500};
  int b = blockIdx.x;
  int n = ns[b];
  const float* p0 = s0 + offs[b];
  const float* p1 = s1 + offs[b];
  int tid = threadIdx.x;
  float m = -3.4e38f;
  for (int i = tid; i < n; i += 1024) m = fmaxf(m, p0[i]);
  red[tid] = m; __syncthreads();
  for (int s = 512; s > 0; s >>= 1) { if (tid < s) red[tid] = fmaxf(red[tid], red[tid + s]); __syncthreads(); }
  float m0 = red[0]; __syncthreads();
  float z = 0.f;
  for (int i = tid; i < n; i += 1024) z += expf(p0[i] - m0);
  red[tid] = z; __syncthreads();
  for (int s = 512; s > 0; s >>= 1) { if (tid < s) red[tid] += red[tid + s]; __syncthreads(); }
  float Z0 = red[0]; __syncthreads();
  m = -3.4e38f;
  for (int i = tid; i < n; i += 1024) m = fmaxf(m, p1[i]);
  red[tid] = m; __syncthreads();
  for (int s = 512; s > 0; s >>= 1) { if (tid < s) red[tid] = fmaxf(red[tid], red[tid + s]); __syncthreads(); }
  float m1 = red[0]; __syncthreads();
  z = 0.f;
  for (int i = tid; i < n; i += 1024) z += expf(p1[i] - m1);
  red[tid] = z; __syncthreads();
  for (int s = 512; s > 0; s >>= 1) { if (tid < s) red[tid] += red[tid + s]; __syncthreads(); }
  if (tid == 0) { den[b * 4] = m0; den[b * 4 + 1] = Z0; den[b * 4 + 2] = m1; den[b * 4 + 3] = red[0]; }
}

// 2 elems/thread: writes fe (f32), feb (bf16 mirror) and rel copy
__global__ __launch_bounds__(256) void fuse_emb_all(
    const float* __restrict__ e0, const float* __restrict__ e1,
    const float* __restrict__ s0, const float* __restrict__ s1,
    const float* __restrict__ den, const float* __restrict__ rel,
    float* __restrict__ fe, unsigned short* __restrict__ feb,
    float* __restrict__ rel_out)
{
  int t = blockIdx.x * 256 + threadIdx.x;
  const int tot2 = 18500 * 64;
  if (t < tot2) {
    int idx = t * 2;
    int row = idx >> 7;
    int e = (row < 8000) ? 0 : (row < 11000) ? 1 : (row < 12500) ? 2 : 3;
    float a0 = expf(s0[row] - den[e * 4]) / den[e * 4 + 1];
    float a1 = expf(s1[row] - den[e * 4 + 2]) / den[e * 4 + 3];
    float2 v0 = *reinterpret_cast<const float2*>(e0 + idx);
    float2 v1 = *reinterpret_cast<const float2*>(e1 + idx);
    float r0 = fmaxf(a0 * v0.x + a1 * v1.x, 0.f);
    float r1 = fmaxf(a0 * v0.y + a1 * v1.y, 0.f);
    *reinterpret_cast<float2*>(fe + idx) = make_float2(r0, r1);
    unsigned pb = (unsigned)f2bf(r0) | ((unsigned)f2bf(r1) << 16);
    *reinterpret_cast<unsigned*>(feb + idx) = pb;
  } else if (t < tot2 + 768) {
    int k = (t - tot2) * 2;
    *reinterpret_cast<float2*>(rel_out + k) = *reinterpret_cast<const float2*>(rel + k);
  }
}

// ---------------------------------------------------------------------------
// Edge losses (bf16 gathers; lane covers dims {2l, 2l+1})
// ---------------------------------------------------------------------------
__global__ __launch_bounds__(256) void edge_both(
    const int* __restrict__ ud, const int* __restrict__ us,
    const unsigned short* __restrict__ feb, const unsigned short* __restrict__ relb,
    float* __restrict__ partial, int En)
{
  int lane = threadIdx.x & 63;
  int wid = threadIdx.x >> 6;
  bool is_d = (blockIdx.x < 1024);
  int bb = is_d ? blockIdx.x : blockIdx.x - 1024;
  int gw = bb * 4 + wid;
  const int nw = 1024 * 4;
  float acc = 0.f;
  if (is_d) {
    for (int e = gw; e < En; e += nw) {
      int4 ei = *reinterpret_cast<const int4*>(ud + (size_t)e * 4);
      float2 fi = bfpair(reinterpret_cast<const unsigned*>(feb + (size_t)ei.x * 128)[lane]);
      float2 fj = bfpair(reinterpret_cast<const unsigned*>(feb + (size_t)ei.y * 128)[lane]);
      float2 rr = bfpair(reinterpret_cast<const unsigned*>(relb + (size_t)ei.w * 128)[lane]);
      float d = rr.x * tanhf(fi.x + fj.x) + rr.y * tanhf(fi.y + fj.y);
#pragma unroll
      for (int o = 32; o > 0; o >>= 1) d += __shfl_down(d, o);
      if (lane == 0) {
        float x = (float)ei.z * d;
        acc += (x >= 0.f) ? log1pf(expf(-x)) : (-x + log1pf(expf(x)));
      }
    }
  } else {
    for (int e = gw; e < En; e += nw) {
      int i = us[(size_t)e * 3], j = us[(size_t)e * 3 + 1], lab = us[(size_t)e * 3 + 2];
      float2 fi = bfpair(reinterpret_cast<const unsigned*>(feb + (size_t)i * 128)[lane]);
      float2 fj = bfpair(reinterpret_cast<const unsigned*>(feb + (size_t)j * 128)[lane]);
      float d = fi.x * fj.x + fi.y * fj.y;
#pragma unroll
      for (int o = 32; o > 0; o >>= 1) d += __shfl_down(d, o);
      if (lane == 0) {
        float x = (float)lab * d;
        acc += (x >= 0.f) ? log1pf(expf(-x)) : (-x + log1pf(expf(x)));
      }
    }
  }
  __shared__ float red[4];
  if (lane == 0) red[wid] = acc;
  __syncthreads();
  if (threadIdx.x == 0) partial[blockIdx.x] = red[0] + red[1] + red[2] + red[3];
}

__global__ __launch_bounds__(1024) void final_reduce(
    const float* __restrict__ partial, const float* __restrict__ cebuf,
    float* __restrict__ out)
{
  __shared__ float red[1024];
  __shared__ float total;
  int tid = threadIdx.x;
  if (tid == 0) total = 0.f;
  __syncthreads();
  float a = partial[tid] + partial[tid + 1024];
  red[tid] = a; __syncthreads();
  for (int s = 512; s > 0; s >>= 1) { if (tid < s) red[tid] += red[tid + s]; __syncthreads(); }
  if (tid == 0) total += red[0];
  __syncthreads();
  const int ns[5] = {3000, 8000, 6000, 8000, 3000};
#pragma unroll
  for (int seg = 0; seg < 5; ++seg) {
    const float* v = cebuf + seg * 8000;
    float s = 0.f;
    for (int i = tid; i < ns[seg]; i += 1024) s += v[i];
    red[tid] = s; __syncthreads();
    for (int st = 512; st > 0; st >>= 1) { if (tid < st) red[tid] += red[tid + st]; __syncthreads(); }
    if (tid == 0) total -= red[0] / (float)ns[seg];
    __syncthreads();
  }
  if (tid == 0) out[0] = total;
}

// ---------------------------------------------------------------------------
extern "C" void kernel_launch(void* const* d_in, const int* in_sizes, int n_in,
                              void* d_out, int out_size, void* d_ws, size_t ws_size,
                              hipStream_t stream)
{
  const float* feat_P = (const float*)d_in[0];
  const float* feat_V = (const float*)d_in[1];
  const float* feat_C = (const float*)d_in[2];
  const float* feat_A = (const float*)d_in[3];
  const float* W1 = (const float*)d_in[4];
  const float* b1 = (const float*)d_in[5];
  const float* W2 = (const float*)d_in[6];
  const float* b2 = (const float*)d_in[7];
  const float* W3 = (const float*)d_in[8];
  const float* b3 = (const float*)d_in[9];
  const float* L00W = (const float*)d_in[10];
  const float* L00b = (const float*)d_in[11];
  const float* L01W = (const float*)d_in[12];
  const float* L01b = (const float*)d_in[13];
  const float* L10W = (const float*)d_in[14];
  const float* L10b = (const float*)d_in[15];
  const float* L11W = (const float*)d_in[16];
  const float* L11b = (const float*)d_in[17];
  const float* L12W = (const float*)d_in[18];
  const float* L12b = (const float*)d_in[19];
  const float* g0_Wih = (const float*)d_in[20];
  const float* g0_Whh = (const float*)d_in[21];
  const float* g0_bih = (const float*)d_in[22];
  const float* g0_bhh = (const float*)d_in[23];
  const float* g1_Wih = (const float*)d_in[24];
  const float* g1_Whh = (const float*)d_in[25];
  const float* g1_bih = (const float*)d_in[26];
  const float* g1_bhh = (const float*)d_in[27];
  const float* rel_emb = (const float*)d_in[28];
  const float* adj00 = (const float*)d_in[29];
  const float* adj01 = (const float*)d_in[30];
  const float* adj10 = (const float*)d_in[31];
  const float* adj11 = (const float*)d_in[32];
  const float* adj12 = (const float*)d_in[33];
  const float* clsA = (const float*)d_in[34];
  const float* clsP = (const float*)d_in[35];
  const float* clsV = (const float*)d_in[36];
  const int* u_s = (const int*)d_in[37];
  const int* u_d = (const int*)d_in[38];

  float* out = (float*)d_out;
  float* fe = out + 1;
  float* rel_out = out + 1 + 18500 * 128;

  float* ws = (float*)d_ws;
  size_t o = 0;
  auto alloc = [&](size_t n) { float* p = ws + o; o += n; return p; };
  float* selfb   = alloc((size_t)18500 * 128);
  float* stcat   = alloc((size_t)18500 * 128);   // P0|V1|C1|A0
  float* stP1    = alloc((size_t)8000 * 128);
  float* gi      = alloc((size_t)26500 * 384);
  float* logits  = alloc((size_t)8000 * 1500);   // stage1 + stage4 reuse
  float* logits0 = alloc((size_t)3000 * 1500);
  float* logits2 = alloc((size_t)8000 * 1500);   // stage2 static (6000) + stage3 (8000)
  float* scaled1 = alloc((size_t)8000 * 128);
  float* scaled3 = alloc((size_t)8000 * 128);
  float* scaled0 = alloc((size_t)3000 * 128);
  float* scaled2 = alloc((size_t)6000 * 128);
  float* scaled4 = alloc((size_t)3000 * 128);
  float* h0      = alloc((size_t)8000 * 128);
  float* h2      = alloc((size_t)8000 * 128);
  float* h1      = alloc((size_t)6000 * 128);
  float* h3      = alloc((size_t)3000 * 128);
  float* h4      = alloc((size_t)1500 * 128);
  float* cebuf   = alloc(5 * 8000);
  float* s0b = alloc(18500);
  float* s1b = alloc(18500);
  float* den = alloc(16);
  float* partial = alloc(2048);
  auto allocb = [&](size_t nelem) { unsigned short* p = (unsigned short*)(ws + o); o += (nelem + 1) / 2; return p; };
  unsigned short* featb  = allocb((size_t)18500 * 128);
  unsigned short* stcatb = allocb((size_t)18500 * 128);
  unsigned short* stP1b  = allocb((size_t)8000 * 128);
  unsigned short* feb    = allocb((size_t)18500 * 128);
  unsigned short* h0b    = allocb((size_t)8000 * 128);
  unsigned short* h2b    = allocb((size_t)8000 * 128);
  unsigned short* h1b    = allocb((size_t)6000 * 128);
  unsigned short* h3b    = allocb((size_t)3000 * 128);
  unsigned short* h4b    = allocb((size_t)1500 * 128);
  unsigned short* relb   = allocb(12 * 128);
  unsigned short* W1b = allocb(128 * 128);
  unsigned short* L00Wb = allocb(1500 * 128);
  unsigned short* L01Wb = allocb(1500 * 128);
  unsigned short* L10Wb = allocb(1500 * 128);
  unsigned short* L11Wb = allocb(1500 * 128);
  unsigned short* L12Wb = allocb(1500 * 128);
  unsigned short* g0Wihb = allocb(384 * 128);
  unsigned short* g0Whhb = allocb(384 * 128);
  unsigned short* g1Wihb = allocb(384 * 128);
  unsigned short* g1Whhb = allocb(384 * 128);
  unsigned short* featPb = featb;
  unsigned short* featVb = featb + (size_t)8000 * 128;
  unsigned short* featCb = featb + (size_t)11000 * 128;
  unsigned short* featAb = featb + (size_t)12500 * 128;
  float* stP0 = stcat;
  float* stV1 = stcat + (size_t)8000 * 128;
  float* stC1 = stcat + (size_t)11000 * 128;
  float* stA0 = stcat + (size_t)12500 * 128;
  unsigned short* stP0b = stcatb;
  unsigned short* stV1b = stcatb + (size_t)8000 * 128;
  unsigned short* stC1b = stcatb + (size_t)11000 * 128;
  unsigned short* stA0b = stcatb + (size_t)12500 * 128;
  (void)ws_size; (void)in_sizes; (void)n_in; (void)out_size;

  dim3 blk(256);

  // --- 1. batched f32->bf16 conversion ---
  CvtArgs ca{};
  int nseg = 0, totblk = 0;
  auto addseg = [&](const float* src, unsigned short* dst, int n) {
    ca.seg[nseg].src = src; ca.seg[nseg].dst = dst; ca.seg[nseg].n = n;
    ca.seg[nseg].nblk = (n + 1023) / 1024; totblk += ca.seg[nseg].nblk; ++nseg;
  };
  addseg(feat_P, featPb, 8000 * 128);
  addseg(feat_V, featVb, 3000 * 128);
  addseg(feat_C, featCb, 1500 * 128);
  addseg(feat_A, featAb, 6000 * 128);
  addseg(W1, W1b, 128 * 128);
  addseg(L00W, L00Wb, 1500 * 128);
  addseg(L01W, L01Wb, 1500 * 128);
  addseg(L10W, L10Wb, 1500 * 128);
  addseg(L11W, L11Wb, 1500 * 128);
  addseg(L12W, L12Wb, 1500 * 128);
  addseg(g0_Wih, g0Wihb, 384 * 128);
  addseg(g0_Whh, g0Whhb, 384 * 128);
  addseg(g1_Wih, g1Wihb, 384 * 128);
  addseg(g1_Whh, g1Whhb, 384 * 128);
  addseg(rel_emb, relb, 12 * 128);
  ca.nseg = nseg;
  hipLaunchKernelGGL(convert_bf16_many, dim3(totblk), blk, 0, stream, ca);

  const size_t giOff[5] = {0, 8000, 14000, 22000, 25000};

  // --- 2. ALL static GEMMs in one generalized launch ---
  {
    GSegs gs{};
    int nb = 0, k = 0;
    auto add = [&](const unsigned short* X, const unsigned short* W, const float* bias,
                   float* C, int N, int O) {
      int xb = (N + 127) / 128, yb = (O + 63) / 64;
      gs.s[k] = GSeg{X, W, bias, C, N, O, nb, xb};
      nb += xb * yb; ++k;
    };
    add(featb,  W1b,    b1,     selfb,             18500, 128);
    add(featPb, g0Wihb, g0_bih, gi + giOff[0] * 384, 8000, 384);
    add(featAb, g0Wihb, g0_bih, gi + giOff[1] * 384, 6000, 384);
    add(featPb, g1Wihb, g1_bih, gi + giOff[2] * 384, 8000, 384);
    add(featVb, g1Wihb, g1_bih, gi + giOff[3] * 384, 3000, 384);
    add(featCb, g1Wihb, g1_bih, gi + giOff[4] * 384, 1500, 384);
    add(featVb, L00Wb,  L00b,   logits0,            3000, 1500);
    add(featAb, L10Wb,  L10b,   logits2,            6000, 1500);
    gs.nseg = k;
    hipLaunchKernelGGL(gemm_bf16_gseg, dim3(nb), blk, 0, stream, gs);
  }

  // --- 3. rowops stages 0+2 ---
  hipLaunchKernelGGL(rowops2, dim3((9000 * 64 + 255) / 256), blk, 0, stream,
                     logits0, clsV, feat_V, scaled0, cebuf + 0 * 8000, 3000,
                     logits2, clsA, feat_A, scaled2, cebuf + 2 * 8000, 6000);
  // --- 4. spmv stages 0+2 ---
  hipLaunchKernelGGL(spmv_scan2, dim3(16000), blk, 0, stream,
                     adj00, scaled0, h0, h0b, 8000, 3000,
                     adj10, scaled2, h2, h2b, 6000);
  // --- 5. gh_gru stages 0+2 -> stP0, stP1 ---
  hipLaunchKernelGGL(gh_gru2, dim3(500), blk, 0, stream,
                     h0b, g0Whhb, g0_bhh, gi + giOff[0] * 384, h0, stP0, stP0b, 8000, 250,
                     h2b, g1Whhb, g1_bhh, gi + giOff[2] * 384, h2, stP1, stP1b, 8000);
  // --- 6. logits stages 1+3 ---
  {
    GSegs gs{};
    gs.s[0] = GSeg{stP0b, L01Wb, L01b, logits,  8000, 1500, 0,    63};
    gs.s[1] = GSeg{stP1b, L11Wb, L11b, logits2, 8000, 1500, 1512, 63};
    gs.nseg = 2;
    hipLaunchKernelGGL(gemm_bf16_gseg, dim3(3024), blk, 0, stream, gs);
  }
  // --- 7. rowops stages 1+3 ---
  hipLaunchKernelGGL(rowops2, dim3((16000 * 64 + 255) / 256), blk, 0, stream,
                     logits,  clsP, stP0, scaled1, cebuf + 1 * 8000, 8000,
                     logits2, clsP, stP1, scaled3, cebuf + 3 * 8000, 8000);
  // --- 8. spmv stages 1+3 ---
  hipLaunchKernelGGL(spmv_scan2, dim3(9000), blk, 0, stream,
                     adj01, scaled1, h1, h1b, 6000, 8000,
                     adj11, scaled3, h3, h3b, 8000);
  // --- 9. gh_gru stages 1+3 -> stA0, stV1 ---
  hipLaunchKernelGGL(gh_gru2, dim3(188 + 94), blk, 0, stream,
                     h1b, g0Whhb, g0_bhh, gi + giOff[1] * 384, h1, stA0, stA0b, 6000, 188,
                     h3b, g1Whhb, g1_bhh, gi + giOff[3] * 384, h3, stV1, stV1b, 3000);
  // --- 10-13. stage 4 ---
  hipLaunchKernelGGL(gemm_bf16, dim3(24, 24), blk, 0, stream, stV1b, L12Wb, L12b, logits, 3000, 1500);
  hipLaunchKernelGGL(rowops_wave, dim3((3000 * 64 + 255) / 256), blk, 0, stream,
                     logits, clsV, stV1, scaled4, cebuf + 4 * 8000, 3000);
  hipLaunchKernelGGL(spmv_scan, dim3(1500), blk, 0, stream, adj12, scaled4, h4, h4b, 1500, 3000);
  hipLaunchKernelGGL(gh_gru, dim3(47), blk, 0, stream,
                     h4b, g1Whhb, g1_bhh, gi + giOff[4] * 384, h4, stC1, stC1b, 1500);

  // --- 14-16. fuse pipeline ---
  hipLaunchKernelGGL(fuse_scores_all, dim3((18500 + 3) / 4), blk, 0, stream,
                     selfb, stcat, W2, b2, W3, b3, s0b, s1b);
  hipLaunchKernelGGL(denom4, dim3(4), dim3(1024), 0, stream, s0b, s1b, den);
  hipLaunchKernelGGL(fuse_emb_all, dim3((18500 * 64 + 768 + 255) / 256), blk, 0, stream,
                     selfb, stcat, s0b, s1b, den, rel_emb, fe, feb, rel_out);

  // --- 17. edges (bf16 gathers) ---
  hipLaunchKernelGGL(edge_both, dim3(2048), blk, 0, stream, u_d, u_s, feb, relb, partial, 150000);

  // --- 18. final ---
  hipLaunchKernelGGL(final_reduce, dim3(1), dim3(1024), 0, stream, partial, cebuf, out);
}